// Round 8
// baseline (346.148 us; speedup 1.0000x reference)
//
#include <hip/hip_runtime.h>
#include <stdint.h>

#define BB 8
#define NN 262144
#define KSEL 6000
#define KPAD2 6144
#define NW2 24               // 24 words of 256 boxes
#define PROP 1000
#define NMS_THR 0.7f
#define CAND_CAP 8192
#define BPB 64               // blocks per batch for hist/compact (4096 items each)
#define STAGE_CAP 768

// ---------- helpers ----------
// Exact replacement for RN(inter/den) > 0.7f (den > 0 always):
//   RN(q) > c  <=>  q >= M, M = c + 2^-25 (midpoint; tie rounds to even = c_next > c).
//   M has 25-bit significand, den 24 bits -> M*den exact in f64; comparison exact.
__device__ __forceinline__ uint32_t sup_bit(const float4 bi, float ai, const float4 bj, float aj) {
    float y1 = fmaxf(bi.x, bj.x), x1 = fmaxf(bi.y, bj.y);
    float y2 = fminf(bi.z, bj.z), x2 = fminf(bi.w, bj.w);
    float inter = __fmul_rn(fmaxf(__fsub_rn(y2, y1), 0.f), fmaxf(__fsub_rn(x2, x1), 0.f));
    float den = __fadd_rn(__fsub_rn(__fadd_rn(ai, aj), inter), 1e-10f);
    const double MSUP = 23488103.0 / 33554432.0;   // 0.7f + 2^-25, exact
    return (double)inter >= MSUP * (double)den;
}

__device__ __forceinline__ uint32_t score_bin(float sc) {
    uint32_t u = (uint32_t)(sc * 16777216.0f);
    u = u > 16777215u ? 16777215u : u;
    return u >> 16;
}

// ---------- K1: per-block LDS histogram -> global 256-bin per-batch hist ----------
__global__ void k_hist(const float4* __restrict__ probs, uint32_t* __restrict__ ghist) {
    __shared__ uint32_t lh[256];
    int blk = blockIdx.x;
    int b = blk >> 6;
    int t = threadIdx.x;
    lh[t] = 0u;
    __syncthreads();
    size_t fbase = ((size_t)b * (NN / 2)) + (size_t)(blk & 63) * 2048;
#pragma unroll
    for (int k = 0; k < 8; ++k) {
        float4 v = probs[fbase + k * 256 + t];
        atomicAdd(&lh[score_bin(v.y)], 1u);
        atomicAdd(&lh[score_bin(v.w)], 1u);
    }
    __syncthreads();
    uint32_t c = lh[t];
    if (c) atomicAdd(&ghist[(b << 8) + t], c);
}

// ---------- K3: compact candidates (threshold derived in-block), block-aggregated ----------
__global__ void k_compact(const float4* __restrict__ probs, const uint32_t* __restrict__ ghist,
                          uint32_t* __restrict__ cnt, uint64_t* __restrict__ cand) {
    __shared__ uint64_t stage[STAGE_CAP];
    __shared__ uint32_t lh[256];
    __shared__ uint32_t s_bst, lcnt, lbase;
    int blk = blockIdx.x;
    int b = blk >> 6;
    int t = threadIdx.x;
    lh[t] = ghist[(b << 8) + t];
    if (t == 0) lcnt = 0u;
    __syncthreads();
    if (t == 0) {
        uint32_t cum = 0; uint32_t bst = 0;
        for (int c = 255; c >= 0; --c) {
            cum += lh[c];
            if (cum >= (uint32_t)KSEL) { bst = (uint32_t)c; break; }
        }
        s_bst = bst;
    }
    __syncthreads();
    uint32_t bst = s_bst;
    int ibase = (blk & 63) * 4096;
    size_t fbase = ((size_t)b * (NN / 2)) + (size_t)(blk & 63) * 2048;
#pragma unroll
    for (int k = 0; k < 8; ++k) {
        float4 v = probs[fbase + k * 256 + t];
        int i0 = ibase + (k * 256 + t) * 2;
#pragma unroll
        for (int e = 0; e < 2; ++e) {
            float sc = e ? v.w : v.y;
            if (score_bin(sc) >= bst) {
                uint32_t p = atomicAdd(&lcnt, 1u);
                if (p < STAGE_CAP) {
                    uint32_t bits = __float_as_uint(sc);
                    stage[p] = ((uint64_t)bits << 32) | (uint32_t)(~(uint32_t)(i0 + e));
                }
            }
        }
    }
    __syncthreads();
    if (t == 0) {
        uint32_t m = lcnt > STAGE_CAP ? STAGE_CAP : lcnt;
        lbase = atomicAdd(&cnt[b], m);
        lcnt = m;
    }
    __syncthreads();
    uint32_t m = lcnt, base = lbase;
    for (uint32_t s = t; s < m; s += 256) {
        uint32_t pos = base + s;
        if (pos < CAND_CAP) cand[((uint64_t)b << 13) + pos] = stage[s];
    }
}

// ---------- K4a: bitonic phase A — sort 1024-chunks (stages kk=2..1024) ----------
__launch_bounds__(256)
__global__ void k_sort1(const uint32_t* __restrict__ cnt, uint64_t* __restrict__ cand) {
    __shared__ uint64_t key[1024];
    int b = blockIdx.y, ch = blockIdx.x, t = threadIdx.x;
    uint32_t M = cnt[b]; if (M > CAND_CAP) M = CAND_CAP;
    uint64_t* cb = cand + ((uint64_t)b << 13);
    int base = ch << 10;
    for (int i = t; i < 1024; i += 256) key[i] = ((uint32_t)(base + i) < M) ? cb[base + i] : 0ull;
    __syncthreads();
    for (int kk = 2; kk <= 1024; kk <<= 1) {
        for (int j = kk >> 1; j > 0; j >>= 1) {
            for (int e = t; e < 1024; e += 256) {
                int ixj = e ^ j;
                if (ixj > e) {
                    uint64_t a = key[e], c = key[ixj];
                    bool ddd = (((base + e) & kk) == 0);   // global-e direction
                    if ((a < c) == ddd) { key[e] = c; key[ixj] = a; }
                }
            }
            __syncthreads();
        }
    }
    for (int i = t; i < 1024; i += 256) cb[base + i] = key[i];
}

// ---------- K4b: bitonic merge (kk=2048..8192) + gather + decode ----------
__launch_bounds__(1024)
__global__ void k_sort2(const uint64_t* __restrict__ cand,
                        const float4* __restrict__ rpn_bbox, const float4* __restrict__ anchors,
                        float4* __restrict__ boxes, float* __restrict__ scoresS,
                        float* __restrict__ areas) {
    __shared__ uint64_t key[8192];
    int b = blockIdx.x, t = threadIdx.x;
    const uint64_t* cb = cand + ((uint64_t)b << 13);
    for (int s = t; s < 8192; s += 1024) key[s] = cb[s];
    __syncthreads();
    for (int kk = 2048; kk <= 8192; kk <<= 1) {
        for (int j = kk >> 1; j > 0; j >>= 1) {
            for (int e = t; e < 8192; e += 1024) {
                int ixj = e ^ j;
                if (ixj > e) {
                    uint64_t a = key[e], c = key[ixj];
                    bool ddd = ((e & kk) == 0);
                    if ((a < c) == ddd) { key[e] = c; key[ixj] = a; }
                }
            }
            __syncthreads();
        }
    }
    // gather + decode (numpy op order; no FMA contraction)
    for (int r = t; r < KPAD2; r += 1024) {
        float4 bx = make_float4(0.f, 0.f, 0.f, 0.f);
        float sc = 0.f, ar = 0.f;
        if (r < KSEL) {
            uint64_t k64 = key[r];
            uint32_t idx = ~(uint32_t)(k64 & 0xFFFFFFFFull);
            sc = __uint_as_float((uint32_t)(k64 >> 32));
            size_t off = ((size_t)b << 18) + idx;
            float4 a = anchors[off];
            float4 d4 = rpn_bbox[off];
            float d0 = __fmul_rn(d4.x, 0.1f), d1 = __fmul_rn(d4.y, 0.1f);
            float d2 = __fmul_rn(d4.z, 0.2f), d3 = __fmul_rn(d4.w, 0.2f);
            float h = __fsub_rn(a.z, a.x), w = __fsub_rn(a.w, a.y);
            float cy = __fadd_rn(__fadd_rn(a.x, __fmul_rn(0.5f, h)), __fmul_rn(d0, h));
            float cx = __fadd_rn(__fadd_rn(a.y, __fmul_rn(0.5f, w)), __fmul_rn(d1, w));
            float h2 = __fmul_rn(h, expf(d2));
            float w2 = __fmul_rn(w, expf(d3));
            float y1 = __fsub_rn(cy, __fmul_rn(0.5f, h2));
            float x1 = __fsub_rn(cx, __fmul_rn(0.5f, w2));
            float y2 = __fadd_rn(cy, __fmul_rn(0.5f, h2));
            float x2 = __fadd_rn(cx, __fmul_rn(0.5f, w2));
            y1 = fminf(fmaxf(y1, 0.f), 1.f); x1 = fminf(fmaxf(x1, 0.f), 1.f);
            y2 = fminf(fmaxf(y2, 0.f), 1.f); x2 = fminf(fmaxf(x2, 0.f), 1.f);
            bx = make_float4(y1, x1, y2, x2);
            ar = __fmul_rn(__fsub_rn(y2, y1), __fsub_rn(x2, x1));
        }
        boxes[b * KPAD2 + r] = bx;
        scoresS[b * KPAD2 + r] = sc;
        areas[b * KPAD2 + r] = ar;
    }
}

// ---------- K5: fused on-demand matrix + greedy NMS, 1 block (1024 thr) per batch ----
// No byte-granular LDS anywhere: suppression flags live in suppw[8] (u32, atomicOr).
__launch_bounds__(1024)
__global__ void k_nms_fused(const float4* __restrict__ boxes, const float* __restrict__ scoresS,
                            const float* __restrict__ areas, float* __restrict__ out) {
    __shared__ float4 selbox[PROP];          // 16 KB
    __shared__ float selarea[PROP];          // 4 KB
    __shared__ float selscore[PROP];         // 4 KB
    __shared__ float4 wbox[256];             // 4 KB
    __shared__ float warea[256];             // 1 KB
    __shared__ float wscore[256];            // 1 KB
    __shared__ uint64_t diagrow[256][4];     // 8 KB
    __shared__ uint32_t suppw[8];            // 32 B  (u32 atomicOr only)
    __shared__ uint32_t newsel[256];         // 1 KB
    __shared__ uint32_t s_count;

    int b = blockIdx.x;
    int tid = threadIdx.x;
    int wid = tid >> 6, lane = tid & 63;
    size_t bb = (size_t)b * KPAD2;
    int count = 0;

    for (int W = 0; W < NW2; ++W) {
        // phase 1: stage this word's 256 boxes/areas/scores; zero suppw
        if (tid < 256) {
            int j = (W << 8) + tid;
            wbox[tid] = boxes[bb + j];
            warea[tid] = areas[bb + j];
            wscore[tid] = scoresS[bb + j];
        }
        if (tid < 8) suppw[tid] = 0u;
        __syncthreads();
        // phase 2a: diag rows (in-word 256x256 suppression bits), 64 IoUs/thread
        {
            int i = tid & 255, half = tid >> 8;          // half in [0,4)
            float4 bi = wbox[i]; float ai = warea[i];
            int j0 = half << 6;
            uint64_t wbits = 0;
#pragma unroll 4
            for (int jj = 0; jj < 64; ++jj)
                wbits |= (uint64_t)sup_bit(bi, ai, wbox[j0 + jj], warea[j0 + jj]) << jj;
            diagrow[i][half] = wbits;
        }
        __syncthreads();
        // phase 2b: crossing vs previously selected — wave (s,rep) structured,
        // combined via per-wave ballot + u32 atomicOr (no byte stores).
        {
            int s = wid & 3;                 // subword
            int rep = wid >> 2;              // 0..3
            int j = (s << 6) + lane;
            float4 bj = wbox[j]; float aj = warea[j];
            uint32_t any = 0;
            int k = rep;
            for (; k + 4 < count; k += 8) {
                any |= sup_bit(selbox[k], selarea[k], bj, aj);
                any |= sup_bit(selbox[k + 4], selarea[k + 4], bj, aj);
            }
            for (; k < count; k += 4)
                any |= sup_bit(selbox[k], selarea[k], bj, aj);
            unsigned long long m = __ballot(any != 0);
            if (lane == 0 && m) {
                atomicOr(&suppw[s * 2], (uint32_t)m);
                atomicOr(&suppw[s * 2 + 1], (uint32_t)(m >> 32));
            }
        }
        __syncthreads();
        int count_old = count;
        // phase 3: wave 0 — serial register-ballot selection; diag rows loaded
        // per-subword (8-VGPR live range, no spill).
        if (wid == 0) {
            uint64_t a0 = ~(((uint64_t)suppw[1] << 32) | suppw[0]);
            uint64_t a1 = ~(((uint64_t)suppw[3] << 32) | suppw[2]);
            uint64_t a2 = ~(((uint64_t)suppw[5] << 32) | suppw[4]);
            uint64_t a3 = ~(((uint64_t)suppw[7] << 32) | suppw[6]);
            if (W == NW2 - 1) { a1 &= (1ull << 48) - 1; a2 = 0; a3 = 0; }   // j < 6000 valid

            // Selecting box (S,bp): lane tests bit bp of word S of its four rows
            // (rows lane, 64+lane, 128+lane, 192+lane); ballots rebuild the
            // suppressed masks for all 4 subwords (IoU symmetric).
#define SUBWORD(S, AS)                                                        \
            if (AS) {                                                         \
                uint64_t r0 = diagrow[lane][S];                               \
                uint64_t r1 = diagrow[64 + lane][S];                          \
                uint64_t r2 = diagrow[128 + lane][S];                         \
                uint64_t r3 = diagrow[192 + lane][S];                         \
                while (AS && count < PROP) {                                  \
                    uint32_t bp = (uint32_t)__builtin_ctzll(AS);              \
                    bp = __builtin_amdgcn_readfirstlane(bp);                  \
                    if (lane == 0) newsel[count - count_old] =                \
                        (uint32_t)((S << 6) + bp);                            \
                    unsigned long long m0 = __ballot(((r0 >> bp) & 1ull) != 0);\
                    unsigned long long m1 = __ballot(((r1 >> bp) & 1ull) != 0);\
                    unsigned long long m2 = __ballot(((r2 >> bp) & 1ull) != 0);\
                    unsigned long long m3 = __ballot(((r3 >> bp) & 1ull) != 0);\
                    a0 &= ~m0; a1 &= ~m1; a2 &= ~m2; a3 &= ~m3;               \
                    AS &= ~(1ull << bp);                                      \
                    ++count;                                                  \
                }                                                             \
            }
            SUBWORD(0, a0)
            SUBWORD(1, a1)
            SUBWORD(2, a2)
            SUBWORD(3, a3)
#undef SUBWORD
            if (lane == 0) s_count = (uint32_t)count;
        }
        __syncthreads();
        count = (int)s_count;
        // phase 4: append newly selected boxes/scores to LDS selection arrays
        for (int r = tid; r < count - count_old; r += 1024) {
            uint32_t j = newsel[r];
            selbox[count_old + r] = wbox[j];
            selarea[count_old + r] = warea[j];
            selscore[count_old + r] = wscore[j];
        }
        __syncthreads();   // protects selbox for next 2b and wbox for next stage
        if (count >= PROP) break;
    }
    // epilogue: write proposals + scores
    float* prop = out + b * (PROP * 4);
    float* psc = out + BB * PROP * 4 + b * PROP;
    for (int r = tid; r < PROP; r += 1024) {
        if (r < count) {
            *(float4*)(prop + r * 4) = selbox[r];
            psc[r] = selscore[r];
        } else {
            *(float4*)(prop + r * 4) = make_float4(0.f, 0.f, 0.f, 0.f);
            psc[r] = 0.f;
        }
    }
}

extern "C" void kernel_launch(void* const* d_in, const int* in_sizes, int n_in,
                              void* d_out, int out_size, void* d_ws, size_t ws_size,
                              hipStream_t stream) {
    const float4* probs = (const float4*)d_in[0];
    const float4* rpn_bbox = (const float4*)d_in[1];
    const float4* anchors = (const float4*)d_in[2];
    float* out = (float*)d_out;

    uint8_t* p = (uint8_t*)d_ws;
    size_t off = 0;
    auto alloc = [&](size_t bytes) -> void* {
        void* q = p + off;
        off += (bytes + 255) & ~(size_t)255;
        return q;
    };
    uint32_t* ghist = (uint32_t*)alloc((size_t)BB * 256 * 4);
    uint32_t* cnt = (uint32_t*)alloc(BB * 4);
    uint64_t* cand = (uint64_t*)alloc((size_t)BB * CAND_CAP * 8);          // 512 KB
    float4* boxes = (float4*)alloc((size_t)BB * KPAD2 * 16);               // 768 KB
    float* scoresS = (float*)alloc((size_t)BB * KPAD2 * 4);
    float* areas = (float*)alloc((size_t)BB * KPAD2 * 4);

    if (off > ws_size) {
        hipMemsetAsync(d_out, 0, (size_t)out_size * 4, stream);
        return;
    }

    hipMemsetAsync(ghist, 0, (size_t)BB * 256 * 4 + 512, stream);

    k_hist<<<BB * BPB, 256, 0, stream>>>(probs, ghist);
    k_compact<<<BB * BPB, 256, 0, stream>>>(probs, ghist, cnt, cand);
    dim3 gs1(8, BB);
    k_sort1<<<gs1, 256, 0, stream>>>(cnt, cand);
    k_sort2<<<BB, 1024, 0, stream>>>(cand, rpn_bbox, anchors, boxes, scoresS, areas);
    k_nms_fused<<<BB, 1024, 0, stream>>>(boxes, scoresS, areas, out);
}

// Round 9
// 276.706 us; speedup vs baseline: 1.2510x; 1.2510x over previous
//
#include <hip/hip_runtime.h>
#include <stdint.h>

#define BB 8
#define NN 262144
#define KSEL 6000
#define KPAD2 6144
#define NW2 24               // 24 words of 256 boxes
#define PROP 1000
#define NMS_THR 0.7f
#define CAND_CAP 8192
#define BPB 64               // blocks per batch for hist/compact (4096 items each)
#define STAGE_CAP 768
#define MAT_U64_PB 282624ull // sum_{W=1..23} 256*W rows * 4 u64 = 512*23*24
#define DIAG_U64_PB 24576ull // 24*256*4

// ---------- helpers ----------
__device__ __forceinline__ unsigned long long shfl_xor_u64(unsigned long long v, int m) {
    unsigned lo = (unsigned)v, hi = (unsigned)(v >> 32);
    lo = __shfl_xor(lo, m);
    hi = __shfl_xor(hi, m);
    return ((unsigned long long)hi << 32) | lo;
}

// Exact replacement for RN(inter/den) > 0.7f (den > 0 always):
//   RN(q) > c  <=>  q >= M, M = c + 2^-25 (midpoint; tie rounds to even = c_next > c).
//   M has 25-bit significand, den 24 bits -> M*den exact in f64; comparison exact.
__device__ __forceinline__ uint32_t sup_bit(const float4 bi, float ai, const float4 bj, float aj) {
    float y1 = fmaxf(bi.x, bj.x), x1 = fmaxf(bi.y, bj.y);
    float y2 = fminf(bi.z, bj.z), x2 = fminf(bi.w, bj.w);
    float inter = __fmul_rn(fmaxf(__fsub_rn(y2, y1), 0.f), fmaxf(__fsub_rn(x2, x1), 0.f));
    float den = __fadd_rn(__fsub_rn(__fadd_rn(ai, aj), inter), 1e-10f);
    const double MSUP = 23488103.0 / 33554432.0;   // 0.7f + 2^-25, exact
    return (double)inter >= MSUP * (double)den;
}

__device__ __forceinline__ uint32_t score_bin(float sc) {
    uint32_t u = (uint32_t)(sc * 16777216.0f);
    u = u > 16777215u ? 16777215u : u;
    return u >> 16;
}

// ---------- K1: per-block LDS histogram -> global 256-bin per-batch hist ----------
__global__ void k_hist(const float4* __restrict__ probs, uint32_t* __restrict__ ghist) {
    __shared__ uint32_t lh[256];
    int blk = blockIdx.x;
    int b = blk >> 6;
    int t = threadIdx.x;
    lh[t] = 0u;
    __syncthreads();
    size_t fbase = ((size_t)b * (NN / 2)) + (size_t)(blk & 63) * 2048;
#pragma unroll
    for (int k = 0; k < 8; ++k) {
        float4 v = probs[fbase + k * 256 + t];
        atomicAdd(&lh[score_bin(v.y)], 1u);
        atomicAdd(&lh[score_bin(v.w)], 1u);
    }
    __syncthreads();
    uint32_t c = lh[t];
    if (c) atomicAdd(&ghist[(b << 8) + t], c);
}

// ---------- K3: compact candidates (threshold derived in-block), block-aggregated ----------
__global__ void k_compact(const float4* __restrict__ probs, const uint32_t* __restrict__ ghist,
                          uint32_t* __restrict__ cnt, uint64_t* __restrict__ cand) {
    __shared__ uint64_t stage[STAGE_CAP];
    __shared__ uint32_t lh[256];
    __shared__ uint32_t s_bst, lcnt, lbase;
    int blk = blockIdx.x;
    int b = blk >> 6;
    int t = threadIdx.x;
    lh[t] = ghist[(b << 8) + t];
    if (t == 0) lcnt = 0u;
    __syncthreads();
    if (t == 0) {
        uint32_t cum = 0; uint32_t bst = 0;
        for (int c = 255; c >= 0; --c) {
            cum += lh[c];
            if (cum >= (uint32_t)KSEL) { bst = (uint32_t)c; break; }
        }
        s_bst = bst;
    }
    __syncthreads();
    uint32_t bst = s_bst;
    int ibase = (blk & 63) * 4096;
    size_t fbase = ((size_t)b * (NN / 2)) + (size_t)(blk & 63) * 2048;
#pragma unroll
    for (int k = 0; k < 8; ++k) {
        float4 v = probs[fbase + k * 256 + t];
        int i0 = ibase + (k * 256 + t) * 2;
#pragma unroll
        for (int e = 0; e < 2; ++e) {
            float sc = e ? v.w : v.y;
            if (score_bin(sc) >= bst) {
                uint32_t p = atomicAdd(&lcnt, 1u);
                if (p < STAGE_CAP) {
                    uint32_t bits = __float_as_uint(sc);
                    stage[p] = ((uint64_t)bits << 32) | (uint32_t)(~(uint32_t)(i0 + e));
                }
            }
        }
    }
    __syncthreads();
    if (t == 0) {
        uint32_t m = lcnt > STAGE_CAP ? STAGE_CAP : lcnt;
        lbase = atomicAdd(&cnt[b], m);
        lcnt = m;
    }
    __syncthreads();
    uint32_t m = lcnt, base = lbase;
    for (uint32_t s = t; s < m; s += 256) {
        uint32_t pos = base + s;
        if (pos < CAND_CAP) cand[((uint64_t)b << 13) + pos] = stage[s];
    }
}

// ---------- K4a: bitonic phase A — sort 1024-chunks (stages kk=2..1024) ----------
__launch_bounds__(256)
__global__ void k_sort1(const uint32_t* __restrict__ cnt, uint64_t* __restrict__ cand) {
    __shared__ uint64_t key[1024];
    int b = blockIdx.y, ch = blockIdx.x, t = threadIdx.x;
    uint32_t M = cnt[b]; if (M > CAND_CAP) M = CAND_CAP;
    uint64_t* cb = cand + ((uint64_t)b << 13);
    int base = ch << 10;
    for (int i = t; i < 1024; i += 256) key[i] = ((uint32_t)(base + i) < M) ? cb[base + i] : 0ull;
    __syncthreads();
    for (int kk = 2; kk <= 1024; kk <<= 1) {
        for (int j = kk >> 1; j > 0; j >>= 1) {
            for (int e = t; e < 1024; e += 256) {
                int ixj = e ^ j;
                if (ixj > e) {
                    uint64_t a = key[e], c = key[ixj];
                    bool ddd = (((base + e) & kk) == 0);   // global-e direction
                    if ((a < c) == ddd) { key[e] = c; key[ixj] = a; }
                }
            }
            __syncthreads();
        }
    }
    for (int i = t; i < 1024; i += 256) cb[base + i] = key[i];
}

// ---------- K4b: bitonic merge (kk=2048..8192) + gather + decode ----------
__launch_bounds__(1024)
__global__ void k_sort2(const uint64_t* __restrict__ cand,
                        const float4* __restrict__ rpn_bbox, const float4* __restrict__ anchors,
                        float4* __restrict__ boxes, float* __restrict__ scoresS,
                        float* __restrict__ areas) {
    __shared__ uint64_t key[8192];
    int b = blockIdx.x, t = threadIdx.x;
    const uint64_t* cb = cand + ((uint64_t)b << 13);
    for (int s = t; s < 8192; s += 1024) key[s] = cb[s];
    __syncthreads();
    for (int kk = 2048; kk <= 8192; kk <<= 1) {
        for (int j = kk >> 1; j > 0; j >>= 1) {
            for (int e = t; e < 8192; e += 1024) {
                int ixj = e ^ j;
                if (ixj > e) {
                    uint64_t a = key[e], c = key[ixj];
                    bool ddd = ((e & kk) == 0);
                    if ((a < c) == ddd) { key[e] = c; key[ixj] = a; }
                }
            }
            __syncthreads();
        }
    }
    // gather + decode (numpy op order; no FMA contraction)
    for (int r = t; r < KPAD2; r += 1024) {
        float4 bx = make_float4(0.f, 0.f, 0.f, 0.f);
        float sc = 0.f, ar = 0.f;
        if (r < KSEL) {
            uint64_t k64 = key[r];
            uint32_t idx = ~(uint32_t)(k64 & 0xFFFFFFFFull);
            sc = __uint_as_float((uint32_t)(k64 >> 32));
            size_t off = ((size_t)b << 18) + idx;
            float4 a = anchors[off];
            float4 d4 = rpn_bbox[off];
            float d0 = __fmul_rn(d4.x, 0.1f), d1 = __fmul_rn(d4.y, 0.1f);
            float d2 = __fmul_rn(d4.z, 0.2f), d3 = __fmul_rn(d4.w, 0.2f);
            float h = __fsub_rn(a.z, a.x), w = __fsub_rn(a.w, a.y);
            float cy = __fadd_rn(__fadd_rn(a.x, __fmul_rn(0.5f, h)), __fmul_rn(d0, h));
            float cx = __fadd_rn(__fadd_rn(a.y, __fmul_rn(0.5f, w)), __fmul_rn(d1, w));
            float h2 = __fmul_rn(h, expf(d2));
            float w2 = __fmul_rn(w, expf(d3));
            float y1 = __fsub_rn(cy, __fmul_rn(0.5f, h2));
            float x1 = __fsub_rn(cx, __fmul_rn(0.5f, w2));
            float y2 = __fadd_rn(cy, __fmul_rn(0.5f, h2));
            float x2 = __fadd_rn(cx, __fmul_rn(0.5f, w2));
            y1 = fminf(fmaxf(y1, 0.f), 1.f); x1 = fminf(fmaxf(x1, 0.f), 1.f);
            y2 = fminf(fmaxf(y2, 0.f), 1.f); x2 = fminf(fmaxf(x2, 0.f), 1.f);
            bx = make_float4(y1, x1, y2, x2);
            ar = __fmul_rn(__fsub_rn(y2, y1), __fsub_rn(x2, x1));
        }
        boxes[b * KPAD2 + r] = bx;
        scoresS[b * KPAD2 + r] = sc;
        areas[b * KPAD2 + r] = ar;
    }
}

// ---------- K5: suppression bit rows for a word-chunk [w0, ...), 2 rows/thread ----------
// Per word W: (W+1) blocks — sub<W: off-diag rows [256*sub,256*sub+256) vs word W;
//             sub==W: diag rows of word W.  Skips everything once done[b] is set.
__launch_bounds__(128)
__global__ void k_matc(int w0, const float4* __restrict__ boxes, const float* __restrict__ areas,
                       uint64_t* __restrict__ mat, uint64_t* __restrict__ diag,
                       const uint32_t* __restrict__ done) {
    int b = blockIdx.y;
    if (done[b]) return;
    int q = blockIdx.x, W = w0;
    while (q >= W + 1) { q -= W + 1; ++W; }
    int sub = q;                          // [0, W]
    int ibase = sub << 8;
    int t = threadIdx.x;
    __shared__ float4 sb[256];
    __shared__ float sa[256];
    size_t bb = (size_t)b * KPAD2;
    int j0 = W << 8;
    sb[t] = boxes[bb + j0 + t];
    sb[t + 128] = boxes[bb + j0 + t + 128];
    sa[t] = areas[bb + j0 + t];
    sa[t + 128] = areas[bb + j0 + t + 128];
    __syncthreads();
    int iA = ibase + t, iB = ibase + t + 128;
    float4 bA = boxes[bb + iA], bB = boxes[bb + iB];
    float aA = areas[bb + iA], aB = areas[bb + iB];
    uint32_t accA[8] = {0, 0, 0, 0, 0, 0, 0, 0};
    uint32_t accB[8] = {0, 0, 0, 0, 0, 0, 0, 0};
#pragma unroll 4
    for (int jj = 0; jj < 32; ++jj) {
#pragma unroll
        for (int s = 0; s < 4; ++s) {
            int j = (s << 6) + jj;
            float4 bj = sb[j]; float aj = sa[j];
            accA[s * 2] |= sup_bit(bA, aA, bj, aj) << jj;
            accB[s * 2] |= sup_bit(bB, aB, bj, aj) << jj;
        }
    }
#pragma unroll 4
    for (int jj = 32; jj < 64; ++jj) {
#pragma unroll
        for (int s = 0; s < 4; ++s) {
            int j = (s << 6) + jj;
            float4 bj = sb[j]; float aj = sa[j];
            accA[s * 2 + 1] |= sup_bit(bA, aA, bj, aj) << (jj - 32);
            accB[s * 2 + 1] |= sup_bit(bB, aB, bj, aj) << (jj - 32);
        }
    }
    uint64_t* rowA;
    uint64_t* rowB;
    if (sub == W) {
        uint64_t dbase = (uint64_t)b * DIAG_U64_PB;
        rowA = diag + dbase + (uint64_t)(j0 + t) * 4;
        rowB = diag + dbase + (uint64_t)(j0 + t + 128) * 4;
    } else {
        uint64_t mbase = (uint64_t)b * MAT_U64_PB + 512ull * W * (W - 1);
        rowA = mat + mbase + (uint64_t)iA * 4;
        rowB = mat + mbase + (uint64_t)iB * 4;
    }
    ulonglong2 vA0, vA1, vB0, vB1;
    vA0.x = (uint64_t)accA[0] | ((uint64_t)accA[1] << 32);
    vA0.y = (uint64_t)accA[2] | ((uint64_t)accA[3] << 32);
    vA1.x = (uint64_t)accA[4] | ((uint64_t)accA[5] << 32);
    vA1.y = (uint64_t)accA[6] | ((uint64_t)accA[7] << 32);
    vB0.x = (uint64_t)accB[0] | ((uint64_t)accB[1] << 32);
    vB0.y = (uint64_t)accB[2] | ((uint64_t)accB[3] << 32);
    vB1.x = (uint64_t)accB[4] | ((uint64_t)accB[5] << 32);
    vB1.y = (uint64_t)accB[6] | ((uint64_t)accB[7] << 32);
    ((ulonglong2*)rowA)[0] = vA0; ((ulonglong2*)rowA)[1] = vA1;
    ((ulonglong2*)rowB)[0] = vB0; ((ulonglong2*)rowB)[1] = vB1;
}

// ---------- K6: greedy NMS over words [w0,w1), 4 waves/batch, state in ws ----------
__launch_bounds__(256)
__global__ void k_nms_chunk(int w0, int w1, int final_chunk,
                            const float4* __restrict__ boxes, const float* __restrict__ scoresS,
                            const uint64_t* __restrict__ diag, const uint64_t* __restrict__ mat,
                            uint32_t* __restrict__ gsel, uint32_t* __restrict__ ncount,
                            uint32_t* __restrict__ done, float* __restrict__ out) {
    __shared__ uint32_t sel[PROP];           // 4 KB (global indices)
    __shared__ uint64_t diagrow[256][4];     // 8 KB
    __shared__ uint32_t suppw[8];
    __shared__ uint32_t newsel[256];
    __shared__ uint32_t s_count;

    int b = blockIdx.x;
    if (done[b]) return;
    int tid = threadIdx.x;
    int wid = tid >> 6, lane = tid & 63;
    size_t bb = (size_t)b * KPAD2;
    const uint64_t* mb = mat + (uint64_t)b * MAT_U64_PB;
    const uint64_t* dgb = diag + (uint64_t)b * DIAG_U64_PB;
    uint32_t* gs = gsel + b * 1024;

    int count = (int)ncount[b];
    for (int r = tid; r < count; r += 256) sel[r] = gs[r];
    __syncthreads();

    for (int W = w0; W < w1; ++W) {
        // stage diag rows of word W into LDS; zero suppw
        {
            const ulonglong2* src = (const ulonglong2*)(dgb + (uint64_t)(W << 8) * 4);
            ulonglong2* dst = (ulonglong2*)&diagrow[0][0];
            dst[tid * 2] = src[tid * 2];
            dst[tid * 2 + 1] = src[tid * 2 + 1];
        }
        if (tid < 8) suppw[tid] = 0u;
        __syncthreads();
        // crossing gather: rows of prior selections vs word W (4 slots/thread)
        uint64_t acc0 = 0, acc1 = 0, acc2 = 0, acc3 = 0;
        {
            const uint64_t* col = mb + 512ull * W * (W - 1);
            uint32_t c = (uint32_t)count;
            uint32_t i0 = tid, i1 = tid + 256, i2 = tid + 512, i3 = tid + 768;
            if (i0 < c) { const ulonglong2* r = (const ulonglong2*)(col + 4u * sel[i0]);
                          ulonglong2 x = r[0], y = r[1];
                          acc0 |= x.x; acc1 |= x.y; acc2 |= y.x; acc3 |= y.y; }
            if (i1 < c) { const ulonglong2* r = (const ulonglong2*)(col + 4u * sel[i1]);
                          ulonglong2 x = r[0], y = r[1];
                          acc0 |= x.x; acc1 |= x.y; acc2 |= y.x; acc3 |= y.y; }
            if (i2 < c) { const ulonglong2* r = (const ulonglong2*)(col + 4u * sel[i2]);
                          ulonglong2 x = r[0], y = r[1];
                          acc0 |= x.x; acc1 |= x.y; acc2 |= y.x; acc3 |= y.y; }
            if (i3 < c) { const ulonglong2* r = (const ulonglong2*)(col + 4u * sel[i3]);
                          ulonglong2 x = r[0], y = r[1];
                          acc0 |= x.x; acc1 |= x.y; acc2 |= y.x; acc3 |= y.y; }
        }
#pragma unroll
        for (int off = 32; off; off >>= 1) {
            acc0 |= shfl_xor_u64(acc0, off);
            acc1 |= shfl_xor_u64(acc1, off);
            acc2 |= shfl_xor_u64(acc2, off);
            acc3 |= shfl_xor_u64(acc3, off);
        }
        if (lane == 0) {
            if (acc0) { atomicOr(&suppw[0], (uint32_t)acc0); atomicOr(&suppw[1], (uint32_t)(acc0 >> 32)); }
            if (acc1) { atomicOr(&suppw[2], (uint32_t)acc1); atomicOr(&suppw[3], (uint32_t)(acc1 >> 32)); }
            if (acc2) { atomicOr(&suppw[4], (uint32_t)acc2); atomicOr(&suppw[5], (uint32_t)(acc2 >> 32)); }
            if (acc3) { atomicOr(&suppw[6], (uint32_t)acc3); atomicOr(&suppw[7], (uint32_t)(acc3 >> 32)); }
        }
        __syncthreads();
        int count_old = count;
        // wave 0: serial register-ballot selection with LDS diag rows (no spill)
        if (wid == 0) {
            uint64_t a0 = ~(((uint64_t)suppw[1] << 32) | suppw[0]);
            uint64_t a1 = ~(((uint64_t)suppw[3] << 32) | suppw[2]);
            uint64_t a2 = ~(((uint64_t)suppw[5] << 32) | suppw[4]);
            uint64_t a3 = ~(((uint64_t)suppw[7] << 32) | suppw[6]);
            if (W == NW2 - 1) { a1 &= (1ull << 48) - 1; a2 = 0; a3 = 0; }   // j < 6000 valid

#define SUBWORD(S, AS)                                                        \
            if (AS) {                                                         \
                uint64_t r0 = diagrow[lane][S];                               \
                uint64_t r1 = diagrow[64 + lane][S];                          \
                uint64_t r2 = diagrow[128 + lane][S];                         \
                uint64_t r3 = diagrow[192 + lane][S];                         \
                while (AS && count < PROP) {                                  \
                    uint32_t bp = (uint32_t)__builtin_ctzll(AS);              \
                    bp = __builtin_amdgcn_readfirstlane(bp);                  \
                    if (lane == 0) newsel[count - count_old] =                \
                        (uint32_t)((W << 8) + (S << 6) + bp);                 \
                    unsigned long long m0 = __ballot(((r0 >> bp) & 1ull) != 0);\
                    unsigned long long m1 = __ballot(((r1 >> bp) & 1ull) != 0);\
                    unsigned long long m2 = __ballot(((r2 >> bp) & 1ull) != 0);\
                    unsigned long long m3 = __ballot(((r3 >> bp) & 1ull) != 0);\
                    a0 &= ~m0; a1 &= ~m1; a2 &= ~m2; a3 &= ~m3;               \
                    AS &= ~(1ull << bp);                                      \
                    ++count;                                                  \
                }                                                             \
            }
            SUBWORD(0, a0)
            SUBWORD(1, a1)
            SUBWORD(2, a2)
            SUBWORD(3, a3)
#undef SUBWORD
            if (lane == 0) s_count = (uint32_t)count;
        }
        __syncthreads();
        count = (int)s_count;
        // append new selections to LDS + global state
        for (int r = tid; r < count - count_old; r += 256) {
            uint32_t j = newsel[r];
            sel[count_old + r] = j;
            gs[count_old + r] = j;
        }
        __syncthreads();
        if (count >= PROP) break;
    }

    if (count >= PROP || final_chunk) {
        if (tid == 0) { done[b] = 1u; ncount[b] = (uint32_t)count; }
        float* prop = out + b * (PROP * 4);
        float* psc = out + BB * PROP * 4 + b * PROP;
        for (int r = tid; r < PROP; r += 256) {
            if (r < count) {
                uint32_t j = sel[r];
                float4 bx = boxes[bb + j];
                *(float4*)(prop + r * 4) = bx;
                psc[r] = scoresS[bb + j];
            } else {
                *(float4*)(prop + r * 4) = make_float4(0.f, 0.f, 0.f, 0.f);
                psc[r] = 0.f;
            }
        }
    } else {
        if (tid == 0) ncount[b] = (uint32_t)count;
    }
}

extern "C" void kernel_launch(void* const* d_in, const int* in_sizes, int n_in,
                              void* d_out, int out_size, void* d_ws, size_t ws_size,
                              hipStream_t stream) {
    const float4* probs = (const float4*)d_in[0];
    const float4* rpn_bbox = (const float4*)d_in[1];
    const float4* anchors = (const float4*)d_in[2];
    float* out = (float*)d_out;

    uint8_t* p = (uint8_t*)d_ws;
    size_t off = 0;
    auto alloc = [&](size_t bytes) -> void* {
        void* q = p + off;
        off += (bytes + 255) & ~(size_t)255;
        return q;
    };
    uint32_t* ghist = (uint32_t*)alloc((size_t)BB * 256 * 4);              // 8 KB
    uint32_t* cnt = (uint32_t*)alloc(BB * 4);
    uint32_t* ncount = (uint32_t*)alloc(BB * 4);
    uint32_t* ndone = (uint32_t*)alloc(BB * 4);
    uint64_t* cand = (uint64_t*)alloc((size_t)BB * CAND_CAP * 8);          // 512 KB
    float4* boxes = (float4*)alloc((size_t)BB * KPAD2 * 16);               // 768 KB
    float* scoresS = (float*)alloc((size_t)BB * KPAD2 * 4);
    float* areas = (float*)alloc((size_t)BB * KPAD2 * 4);
    uint32_t* gsel = (uint32_t*)alloc((size_t)BB * 1024 * 4);              // 32 KB
    uint64_t* diag = (uint64_t*)alloc((size_t)BB * DIAG_U64_PB * 8);       // 1.57 MB
    uint64_t* mat = (uint64_t*)alloc((size_t)BB * MAT_U64_PB * 8);         // 18.1 MB

    if (off > ws_size) {
        hipMemsetAsync(d_out, 0, (size_t)out_size * 4, stream);
        return;
    }

    // zero ghist + cnt + ncount + ndone every call (contiguous leading region)
    hipMemsetAsync(ghist, 0, (size_t)BB * 256 * 4 + 3 * 256, stream);

    k_hist<<<BB * BPB, 256, 0, stream>>>(probs, ghist);
    k_compact<<<BB * BPB, 256, 0, stream>>>(probs, ghist, cnt, cand);
    dim3 gs1(8, BB);
    k_sort1<<<gs1, 256, 0, stream>>>(cnt, cand);
    k_sort2<<<BB, 1024, 0, stream>>>(cand, rpn_bbox, anchors, boxes, scoresS, areas);

    const int cb[5] = {0, 3, 6, 12, 24};
    for (int c = 0; c < 4; ++c) {
        int w0 = cb[c], w1 = cb[c + 1];
        int nblk = 0;
        for (int W = w0; W < w1; ++W) nblk += W + 1;
        dim3 gm(nblk, BB);
        k_matc<<<gm, 128, 0, stream>>>(w0, boxes, areas, mat, diag, ndone);
        k_nms_chunk<<<BB, 256, 0, stream>>>(w0, w1, (w1 == NW2) ? 1 : 0,
                                            boxes, scoresS, diag, mat,
                                            gsel, ncount, ndone, out);
    }
}

// Round 11
// 195.998 us; speedup vs baseline: 1.7661x; 1.4118x over previous
//
#include <hip/hip_runtime.h>
#include <stdint.h>

#define BB 8
#define NN 262144
#define KSEL 6000
#define KPAD2 6144
#define NW2 24               // 24 words of 256 boxes
#define PROP 1000
#define NMS_THR 0.7f
#define CAND_CAP 8192
#define BPB 64               // blocks per batch for hist/compact (4096 items each)
#define STAGE_CAP 768
#define MAT_U64_PB 282624ull // sum_{W=1..23} 256*W rows * 4 u64 = 512*23*24
#define DIAG_U64_PB 24576ull // 24*256*4

// ---------- helpers ----------
__device__ __forceinline__ unsigned long long shfl_xor_u64(unsigned long long v, int m) {
    unsigned lo = (unsigned)v, hi = (unsigned)(v >> 32);
    lo = __shfl_xor(lo, m);
    hi = __shfl_xor(hi, m);
    return ((unsigned long long)hi << 32) | lo;
}

// Exact replacement for RN(inter/den) > 0.7f (den > 0 always):
//   RN(q) > c  <=>  q >= M, M = c + 2^-25 (midpoint; tie rounds to even = c_next > c).
//   M has 25-bit significand, den 24 bits -> M*den exact in f64; comparison exact.
__device__ __forceinline__ uint32_t sup_bit(const float4 bi, float ai, const float4 bj, float aj) {
    float y1 = fmaxf(bi.x, bj.x), x1 = fmaxf(bi.y, bj.y);
    float y2 = fminf(bi.z, bj.z), x2 = fminf(bi.w, bj.w);
    float inter = __fmul_rn(fmaxf(__fsub_rn(y2, y1), 0.f), fmaxf(__fsub_rn(x2, x1), 0.f));
    float den = __fadd_rn(__fsub_rn(__fadd_rn(ai, aj), inter), 1e-10f);
    const double MSUP = 23488103.0 / 33554432.0;   // 0.7f + 2^-25, exact
    return (double)inter >= MSUP * (double)den;
}

__device__ __forceinline__ uint32_t score_bin(float sc) {
    uint32_t u = (uint32_t)(sc * 16777216.0f);
    u = u > 16777215u ? 16777215u : u;
    return u >> 16;
}

// ---------- K1: per-block LDS histogram -> global 256-bin per-batch hist ----------
__global__ void k_hist(const float4* __restrict__ probs, uint32_t* __restrict__ ghist) {
    __shared__ uint32_t lh[256];
    int blk = blockIdx.x;
    int b = blk >> 6;
    int t = threadIdx.x;
    lh[t] = 0u;
    __syncthreads();
    size_t fbase = ((size_t)b * (NN / 2)) + (size_t)(blk & 63) * 2048;
#pragma unroll
    for (int k = 0; k < 8; ++k) {
        float4 v = probs[fbase + k * 256 + t];
        atomicAdd(&lh[score_bin(v.y)], 1u);
        atomicAdd(&lh[score_bin(v.w)], 1u);
    }
    __syncthreads();
    uint32_t c = lh[t];
    if (c) atomicAdd(&ghist[(b << 8) + t], c);
}

// ---------- K3: compact candidates (threshold derived in-block), block-aggregated ----------
__global__ void k_compact(const float4* __restrict__ probs, const uint32_t* __restrict__ ghist,
                          uint32_t* __restrict__ cnt, uint64_t* __restrict__ cand) {
    __shared__ uint64_t stage[STAGE_CAP];
    __shared__ uint32_t lh[256];
    __shared__ uint32_t s_bst, lcnt, lbase;
    int blk = blockIdx.x;
    int b = blk >> 6;
    int t = threadIdx.x;
    lh[t] = ghist[(b << 8) + t];
    if (t == 0) lcnt = 0u;
    __syncthreads();
    if (t == 0) {
        uint32_t cum = 0; uint32_t bst = 0;
        for (int c = 255; c >= 0; --c) {
            cum += lh[c];
            if (cum >= (uint32_t)KSEL) { bst = (uint32_t)c; break; }
        }
        s_bst = bst;
    }
    __syncthreads();
    uint32_t bst = s_bst;
    int ibase = (blk & 63) * 4096;
    size_t fbase = ((size_t)b * (NN / 2)) + (size_t)(blk & 63) * 2048;
#pragma unroll
    for (int k = 0; k < 8; ++k) {
        float4 v = probs[fbase + k * 256 + t];
        int i0 = ibase + (k * 256 + t) * 2;
#pragma unroll
        for (int e = 0; e < 2; ++e) {
            float sc = e ? v.w : v.y;
            if (score_bin(sc) >= bst) {
                uint32_t p = atomicAdd(&lcnt, 1u);
                if (p < STAGE_CAP) {
                    uint32_t bits = __float_as_uint(sc);
                    stage[p] = ((uint64_t)bits << 32) | (uint32_t)(~(uint32_t)(i0 + e));
                }
            }
        }
    }
    __syncthreads();
    if (t == 0) {
        uint32_t m = lcnt > STAGE_CAP ? STAGE_CAP : lcnt;
        lbase = atomicAdd(&cnt[b], m);
        lcnt = m;
    }
    __syncthreads();
    uint32_t m = lcnt, base = lbase;
    for (uint32_t s = t; s < m; s += 256) {
        uint32_t pos = base + s;
        if (pos < CAND_CAP) cand[((uint64_t)b << 13) + pos] = stage[s];
    }
}

// ---------- K4a: bitonic phase A — sort each 1024-chunk DESCENDING ----------
// Direction uses LOCAL e (not base+e): every chunk independently descending,
// which is k_merge's precondition.
__launch_bounds__(512)
__global__ void k_sort1(const uint32_t* __restrict__ cnt, uint64_t* __restrict__ cand) {
    __shared__ uint64_t key[1024];
    int b = blockIdx.y, ch = blockIdx.x, t = threadIdx.x;
    uint32_t M = cnt[b]; if (M > CAND_CAP) M = CAND_CAP;
    uint64_t* cb = cand + ((uint64_t)b << 13);
    int base = ch << 10;
    for (int i = t; i < 1024; i += 512) key[i] = ((uint32_t)(base + i) < M) ? cb[base + i] : 0ull;
    __syncthreads();
    for (int kk = 2; kk <= 1024; kk <<= 1) {
        for (int j = kk >> 1; j > 0; j >>= 1) {
            for (int e = t; e < 1024; e += 512) {
                int ixj = e ^ j;
                if (ixj > e) {
                    uint64_t a = key[e], c = key[ixj];
                    bool ddd = ((e & kk) == 0);            // local direction: descending chunk
                    if ((a < c) == ddd) { key[e] = c; key[ixj] = a; }
                }
            }
            __syncthreads();
        }
    }
    for (int i = t; i < 1024; i += 512) cb[base + i] = key[i];
}

// ---------- K4b: merge-path level — merge descending runs of length R into 2R ----------
// Keys unique except padding zeros (interchangeable) -> exact. Each thread binary-
// searches its output rank independently: fully parallel, no barriers.
__launch_bounds__(256)
__global__ void k_merge(int R, const uint64_t* __restrict__ src, uint64_t* __restrict__ dst) {
    int b = blockIdx.y;
    int k = (blockIdx.x << 8) + threadIdx.x;        // [0, 8192)
    const uint64_t* base = src + ((uint64_t)b << 13);
    int run = k / (2 * R);
    int ko = k - run * (2 * R);                     // rank within merged run
    const uint64_t* A = base + (size_t)run * 2 * R;
    const uint64_t* B = A + R;
    int lo = ko - R; if (lo < 0) lo = 0;
    int hi = ko < R ? ko : R;
    while (lo < hi) {
        int m = (lo + hi) >> 1;
        int t = ko - m - 1;
        uint64_t bv = (t < 0) ? ~0ull : (t >= R ? 0ull : B[t]);
        if (A[m] > bv) lo = m + 1; else hi = m;     // A[m] comes before rank ko
    }
    int i = lo, j = ko - lo;
    uint64_t av = (i >= R) ? 0ull : A[i];
    uint64_t bv = (j >= R) ? 0ull : B[j];
    dst[((uint64_t)b << 13) + k] = (av > bv) ? av : bv;
}

// ---------- K4c: gather + decode (wide: 6 blocks x 1024 per batch) ----------
__launch_bounds__(1024)
__global__ void k_decode(const uint64_t* __restrict__ keys,
                         const float4* __restrict__ rpn_bbox, const float4* __restrict__ anchors,
                         float4* __restrict__ boxes, float* __restrict__ scoresS,
                         float* __restrict__ areas) {
    int b = blockIdx.y;
    int r = (blockIdx.x << 10) + threadIdx.x;       // [0, 6144)
    float4 bx = make_float4(0.f, 0.f, 0.f, 0.f);
    float sc = 0.f, ar = 0.f;
    if (r < KSEL) {
        uint64_t k64 = keys[((uint64_t)b << 13) + r];
        uint32_t idx = ~(uint32_t)(k64 & 0xFFFFFFFFull);
        sc = __uint_as_float((uint32_t)(k64 >> 32));
        size_t off = ((size_t)b << 18) + idx;
        float4 a = anchors[off];
        float4 d4 = rpn_bbox[off];
        float d0 = __fmul_rn(d4.x, 0.1f), d1 = __fmul_rn(d4.y, 0.1f);
        float d2 = __fmul_rn(d4.z, 0.2f), d3 = __fmul_rn(d4.w, 0.2f);
        float h = __fsub_rn(a.z, a.x), w = __fsub_rn(a.w, a.y);
        float cy = __fadd_rn(__fadd_rn(a.x, __fmul_rn(0.5f, h)), __fmul_rn(d0, h));
        float cx = __fadd_rn(__fadd_rn(a.y, __fmul_rn(0.5f, w)), __fmul_rn(d1, w));
        float h2 = __fmul_rn(h, expf(d2));
        float w2 = __fmul_rn(w, expf(d3));
        float y1 = __fsub_rn(cy, __fmul_rn(0.5f, h2));
        float x1 = __fsub_rn(cx, __fmul_rn(0.5f, w2));
        float y2 = __fadd_rn(cy, __fmul_rn(0.5f, h2));
        float x2 = __fadd_rn(cx, __fmul_rn(0.5f, w2));
        y1 = fminf(fmaxf(y1, 0.f), 1.f); x1 = fminf(fmaxf(x1, 0.f), 1.f);
        y2 = fminf(fmaxf(y2, 0.f), 1.f); x2 = fminf(fmaxf(x2, 0.f), 1.f);
        bx = make_float4(y1, x1, y2, x2);
        ar = __fmul_rn(__fsub_rn(y2, y1), __fsub_rn(x2, x1));
    }
    boxes[b * KPAD2 + r] = bx;
    scoresS[b * KPAD2 + r] = sc;
    areas[b * KPAD2 + r] = ar;
}

// ---------- K5: suppression bit rows for a word-chunk [w0, ...), 2 rows/thread ----------
__launch_bounds__(128)
__global__ void k_matc(int w0, const float4* __restrict__ boxes, const float* __restrict__ areas,
                       uint64_t* __restrict__ mat, uint64_t* __restrict__ diag,
                       const uint32_t* __restrict__ done) {
    int b = blockIdx.y;
    if (done[b]) return;
    int q = blockIdx.x, W = w0;
    while (q >= W + 1) { q -= W + 1; ++W; }
    int sub = q;                          // [0, W]
    int ibase = sub << 8;
    int t = threadIdx.x;
    __shared__ float4 sb[256];
    __shared__ float sa[256];
    size_t bb = (size_t)b * KPAD2;
    int j0 = W << 8;
    sb[t] = boxes[bb + j0 + t];
    sb[t + 128] = boxes[bb + j0 + t + 128];
    sa[t] = areas[bb + j0 + t];
    sa[t + 128] = areas[bb + j0 + t + 128];
    __syncthreads();
    int iA = ibase + t, iB = ibase + t + 128;
    float4 bA = boxes[bb + iA], bB = boxes[bb + iB];
    float aA = areas[bb + iA], aB = areas[bb + iB];
    uint32_t accA[8] = {0, 0, 0, 0, 0, 0, 0, 0};
    uint32_t accB[8] = {0, 0, 0, 0, 0, 0, 0, 0};
#pragma unroll 4
    for (int jj = 0; jj < 32; ++jj) {
#pragma unroll
        for (int s = 0; s < 4; ++s) {
            int j = (s << 6) + jj;
            float4 bj = sb[j]; float aj = sa[j];
            accA[s * 2] |= sup_bit(bA, aA, bj, aj) << jj;
            accB[s * 2] |= sup_bit(bB, aB, bj, aj) << jj;
        }
    }
#pragma unroll 4
    for (int jj = 32; jj < 64; ++jj) {
#pragma unroll
        for (int s = 0; s < 4; ++s) {
            int j = (s << 6) + jj;
            float4 bj = sb[j]; float aj = sa[j];
            accA[s * 2 + 1] |= sup_bit(bA, aA, bj, aj) << (jj - 32);
            accB[s * 2 + 1] |= sup_bit(bB, aB, bj, aj) << (jj - 32);
        }
    }
    uint64_t* rowA;
    uint64_t* rowB;
    if (sub == W) {
        uint64_t dbase = (uint64_t)b * DIAG_U64_PB;
        rowA = diag + dbase + (uint64_t)(j0 + t) * 4;
        rowB = diag + dbase + (uint64_t)(j0 + t + 128) * 4;
    } else {
        uint64_t mbase = (uint64_t)b * MAT_U64_PB + 512ull * W * (W - 1);
        rowA = mat + mbase + (uint64_t)iA * 4;
        rowB = mat + mbase + (uint64_t)iB * 4;
    }
    ulonglong2 vA0, vA1, vB0, vB1;
    vA0.x = (uint64_t)accA[0] | ((uint64_t)accA[1] << 32);
    vA0.y = (uint64_t)accA[2] | ((uint64_t)accA[3] << 32);
    vA1.x = (uint64_t)accA[4] | ((uint64_t)accA[5] << 32);
    vA1.y = (uint64_t)accA[6] | ((uint64_t)accA[7] << 32);
    vB0.x = (uint64_t)accB[0] | ((uint64_t)accB[1] << 32);
    vB0.y = (uint64_t)accB[2] | ((uint64_t)accB[3] << 32);
    vB1.x = (uint64_t)accB[4] | ((uint64_t)accB[5] << 32);
    vB1.y = (uint64_t)accB[6] | ((uint64_t)accB[7] << 32);
    ((ulonglong2*)rowA)[0] = vA0; ((ulonglong2*)rowA)[1] = vA1;
    ((ulonglong2*)rowB)[0] = vB0; ((ulonglong2*)rowB)[1] = vB1;
}

// ---------- K6: greedy NMS over words [w0,w1), state in ws; lean pick loop ----------
__launch_bounds__(256)
__global__ void k_nms_chunk(int w0, int w1, int final_chunk,
                            const float4* __restrict__ boxes, const float* __restrict__ scoresS,
                            const uint64_t* __restrict__ diag, const uint64_t* __restrict__ mat,
                            uint32_t* __restrict__ gsel, uint32_t* __restrict__ ncount,
                            uint32_t* __restrict__ done, float* __restrict__ out) {
    __shared__ uint32_t sel[PROP];           // 4 KB (global indices)
    __shared__ uint64_t diagrow[256][4];     // 8 KB
    __shared__ uint32_t suppw[8];
    __shared__ uint32_t s_count;

    int b = blockIdx.x;
    if (done[b]) return;
    int tid = threadIdx.x;
    int wid = tid >> 6, lane = tid & 63;
    size_t bb = (size_t)b * KPAD2;
    const uint64_t* mb = mat + (uint64_t)b * MAT_U64_PB;
    const uint64_t* dgb = diag + (uint64_t)b * DIAG_U64_PB;
    uint32_t* gs = gsel + b * 1024;

    int count = (int)ncount[b];
    for (int r = tid; r < count; r += 256) sel[r] = gs[r];
    __syncthreads();

    for (int W = w0; W < w1; ++W) {
        // stage diag rows of word W into LDS; zero suppw
        {
            const ulonglong2* src = (const ulonglong2*)(dgb + (uint64_t)(W << 8) * 4);
            ulonglong2* dst = (ulonglong2*)&diagrow[0][0];
            dst[tid * 2] = src[tid * 2];
            dst[tid * 2 + 1] = src[tid * 2 + 1];
        }
        if (tid < 8) suppw[tid] = 0u;
        __syncthreads();
        // crossing gather: rows of prior selections vs word W (4 slots/thread)
        uint64_t acc0 = 0, acc1 = 0, acc2 = 0, acc3 = 0;
        {
            const uint64_t* col = mb + 512ull * W * (W - 1);
            uint32_t c = (uint32_t)count;
            uint32_t i0 = tid, i1 = tid + 256, i2 = tid + 512, i3 = tid + 768;
            if (i0 < c) { const ulonglong2* r = (const ulonglong2*)(col + 4u * sel[i0]);
                          ulonglong2 x = r[0], y = r[1];
                          acc0 |= x.x; acc1 |= x.y; acc2 |= y.x; acc3 |= y.y; }
            if (i1 < c) { const ulonglong2* r = (const ulonglong2*)(col + 4u * sel[i1]);
                          ulonglong2 x = r[0], y = r[1];
                          acc0 |= x.x; acc1 |= x.y; acc2 |= y.x; acc3 |= y.y; }
            if (i2 < c) { const ulonglong2* r = (const ulonglong2*)(col + 4u * sel[i2]);
                          ulonglong2 x = r[0], y = r[1];
                          acc0 |= x.x; acc1 |= x.y; acc2 |= y.x; acc3 |= y.y; }
            if (i3 < c) { const ulonglong2* r = (const ulonglong2*)(col + 4u * sel[i3]);
                          ulonglong2 x = r[0], y = r[1];
                          acc0 |= x.x; acc1 |= x.y; acc2 |= y.x; acc3 |= y.y; }
        }
#pragma unroll
        for (int off = 32; off; off >>= 1) {
            acc0 |= shfl_xor_u64(acc0, off);
            acc1 |= shfl_xor_u64(acc1, off);
            acc2 |= shfl_xor_u64(acc2, off);
            acc3 |= shfl_xor_u64(acc3, off);
        }
        if (lane == 0) {
            if (acc0) { atomicOr(&suppw[0], (uint32_t)acc0); atomicOr(&suppw[1], (uint32_t)(acc0 >> 32)); }
            if (acc1) { atomicOr(&suppw[2], (uint32_t)acc1); atomicOr(&suppw[3], (uint32_t)(acc1 >> 32)); }
            if (acc2) { atomicOr(&suppw[4], (uint32_t)acc2); atomicOr(&suppw[5], (uint32_t)(acc2 >> 32)); }
            if (acc3) { atomicOr(&suppw[6], (uint32_t)acc3); atomicOr(&suppw[7], (uint32_t)(acc3 >> 32)); }
        }
        __syncthreads();
        int count_old = count;
        // wave 0: serial register-ballot selection. Lean loop: picked bits are
        // accumulated in scalar masks pk0..pk3 (no LDS write / exec toggle per pick);
        // sel[]/gs[] are appended in parallel afterwards via popcount ranking.
        if (wid == 0) {
            uint64_t a0 = ~(((uint64_t)suppw[1] << 32) | suppw[0]);
            uint64_t a1 = ~(((uint64_t)suppw[3] << 32) | suppw[2]);
            uint64_t a2 = ~(((uint64_t)suppw[5] << 32) | suppw[4]);
            uint64_t a3 = ~(((uint64_t)suppw[7] << 32) | suppw[6]);
            if (W == NW2 - 1) { a1 &= (1ull << 48) - 1; a2 = 0; a3 = 0; }   // j < 6000 valid
            uint64_t pk0 = 0, pk1 = 0, pk2 = 0, pk3 = 0;

#define SUBWORD(S, AS, PK)                                                    \
            if (AS && count < PROP) {                                         \
                uint64_t r0 = diagrow[lane][S];                               \
                uint64_t r1 = diagrow[64 + lane][S];                          \
                uint64_t r2 = diagrow[128 + lane][S];                         \
                uint64_t r3 = diagrow[192 + lane][S];                         \
                while (AS && count < PROP) {                                  \
                    uint32_t bp = (uint32_t)__builtin_ctzll(AS);              \
                    PK |= 1ull << bp;                                         \
                    unsigned long long m0 = __ballot(((r0 >> bp) & 1ull) != 0);\
                    unsigned long long m1 = __ballot(((r1 >> bp) & 1ull) != 0);\
                    unsigned long long m2 = __ballot(((r2 >> bp) & 1ull) != 0);\
                    unsigned long long m3 = __ballot(((r3 >> bp) & 1ull) != 0);\
                    a0 &= ~m0; a1 &= ~m1; a2 &= ~m2; a3 &= ~m3;               \
                    AS &= ~(1ull << bp);                                      \
                    ++count;                                                  \
                }                                                             \
            }
            SUBWORD(0, a0, pk0)
            SUBWORD(1, a1, pk1)
            SUBWORD(2, a2, pk2)
            SUBWORD(3, a3, pk3)
#undef SUBWORD
            // parallel append: picks were made in ascending (S, bp) order
            uint32_t nb = (uint32_t)count_old;
#define APPEND(S, PK) {                                                       \
            if (PK) {                                                         \
                uint32_t my = (uint32_t)((PK >> lane) & 1ull);                \
                uint32_t rank = (uint32_t)__popcll(PK & ((1ull << lane) - 1ull));\
                if (my) {                                                     \
                    uint32_t v = (uint32_t)((W << 8) + (S << 6) + lane);      \
                    sel[nb + rank] = v;                                       \
                    gs[nb + rank] = v;                                        \
                }                                                             \
                nb += (uint32_t)__popcll(PK);                                 \
            } }
            APPEND(0, pk0)
            APPEND(1, pk1)
            APPEND(2, pk2)
            APPEND(3, pk3)
#undef APPEND
            if (lane == 0) s_count = (uint32_t)count;
        }
        __syncthreads();
        count = (int)s_count;
        if (count >= PROP) break;
    }

    if (count >= PROP || final_chunk) {
        if (tid == 0) { done[b] = 1u; ncount[b] = (uint32_t)count; }
        float* prop = out + b * (PROP * 4);
        float* psc = out + BB * PROP * 4 + b * PROP;
        for (int r = tid; r < PROP; r += 256) {
            if (r < count) {
                uint32_t j = sel[r];
                float4 bx = boxes[bb + j];
                *(float4*)(prop + r * 4) = bx;
                psc[r] = scoresS[bb + j];
            } else {
                *(float4*)(prop + r * 4) = make_float4(0.f, 0.f, 0.f, 0.f);
                psc[r] = 0.f;
            }
        }
    } else {
        if (tid == 0) ncount[b] = (uint32_t)count;
    }
}

extern "C" void kernel_launch(void* const* d_in, const int* in_sizes, int n_in,
                              void* d_out, int out_size, void* d_ws, size_t ws_size,
                              hipStream_t stream) {
    const float4* probs = (const float4*)d_in[0];
    const float4* rpn_bbox = (const float4*)d_in[1];
    const float4* anchors = (const float4*)d_in[2];
    float* out = (float*)d_out;

    uint8_t* p = (uint8_t*)d_ws;
    size_t off = 0;
    auto alloc = [&](size_t bytes) -> void* {
        void* q = p + off;
        off += (bytes + 255) & ~(size_t)255;
        return q;
    };
    uint32_t* ghist = (uint32_t*)alloc((size_t)BB * 256 * 4);              // 8 KB
    uint32_t* cnt = (uint32_t*)alloc(BB * 4);
    uint32_t* ncount = (uint32_t*)alloc(BB * 4);
    uint32_t* ndone = (uint32_t*)alloc(BB * 4);
    uint64_t* cand = (uint64_t*)alloc((size_t)BB * CAND_CAP * 8);          // 512 KB
    uint64_t* cand2 = (uint64_t*)alloc((size_t)BB * CAND_CAP * 8);         // 512 KB
    float4* boxes = (float4*)alloc((size_t)BB * KPAD2 * 16);               // 768 KB
    float* scoresS = (float*)alloc((size_t)BB * KPAD2 * 4);
    float* areas = (float*)alloc((size_t)BB * KPAD2 * 4);
    uint32_t* gsel = (uint32_t*)alloc((size_t)BB * 1024 * 4);              // 32 KB
    uint64_t* diag = (uint64_t*)alloc((size_t)BB * DIAG_U64_PB * 8);       // 1.57 MB
    uint64_t* mat = (uint64_t*)alloc((size_t)BB * MAT_U64_PB * 8);         // 18.1 MB

    if (off > ws_size) {
        hipMemsetAsync(d_out, 0, (size_t)out_size * 4, stream);
        return;
    }

    // zero ghist + cnt + ncount + ndone every call (contiguous leading region)
    hipMemsetAsync(ghist, 0, (size_t)BB * 256 * 4 + 3 * 256, stream);

    k_hist<<<BB * BPB, 256, 0, stream>>>(probs, ghist);
    k_compact<<<BB * BPB, 256, 0, stream>>>(probs, ghist, cnt, cand);
    dim3 gs1(8, BB);
    k_sort1<<<gs1, 512, 0, stream>>>(cnt, cand);
    dim3 gmg(32, BB);
    k_merge<<<gmg, 256, 0, stream>>>(1024, cand, cand2);
    k_merge<<<gmg, 256, 0, stream>>>(2048, cand2, cand);
    k_merge<<<gmg, 256, 0, stream>>>(4096, cand, cand2);
    dim3 gdc(6, BB);
    k_decode<<<gdc, 1024, 0, stream>>>(cand2, rpn_bbox, anchors, boxes, scoresS, areas);

    const int cb[5] = {0, 3, 6, 12, 24};
    for (int c = 0; c < 4; ++c) {
        int w0 = cb[c], w1 = cb[c + 1];
        int nblk = 0;
        for (int W = w0; W < w1; ++W) nblk += W + 1;
        dim3 gm(nblk, BB);
        k_matc<<<gm, 128, 0, stream>>>(w0, boxes, areas, mat, diag, ndone);
        k_nms_chunk<<<BB, 256, 0, stream>>>(w0, w1, (w1 == NW2) ? 1 : 0,
                                            boxes, scoresS, diag, mat,
                                            gsel, ncount, ndone, out);
    }
}

// Round 12
// 144.260 us; speedup vs baseline: 2.3995x; 1.3586x over previous
//
#include <hip/hip_runtime.h>
#include <stdint.h>

#define BB 8
#define NN 262144
#define KSEL 6000
#define KPAD2 6144
#define NW2 24               // 24 words of 256 boxes
#define PROP 1000
#define NMS_THR 0.7f
#define CAND_CAP 8192
#define BPB 64               // blocks per batch for hist/compact (4096 items each)
#define STAGE_CAP 768
#define MAT_U64_PB 282624ull // sum_{W=1..23} 256*W rows * 4 u64 = 512*23*24
#define DIAG_U64_PB 24576ull // 24*256*4

// ---------- helpers ----------
__device__ __forceinline__ unsigned long long shfl_xor_u64(unsigned long long v, int m) {
    unsigned lo = (unsigned)v, hi = (unsigned)(v >> 32);
    lo = __shfl_xor(lo, m);
    hi = __shfl_xor(hi, m);
    return ((unsigned long long)hi << 32) | lo;
}
__device__ __forceinline__ uint64_t rdfl64(uint64_t v) {
    uint32_t lo = __builtin_amdgcn_readfirstlane((uint32_t)v);
    uint32_t hi = __builtin_amdgcn_readfirstlane((uint32_t)(v >> 32));
    return ((uint64_t)hi << 32) | lo;
}
__device__ __forceinline__ uint64_t rdlane64(uint64_t v, uint32_t l) {
    uint32_t lo = __builtin_amdgcn_readlane((uint32_t)v, l);
    uint32_t hi = __builtin_amdgcn_readlane((uint32_t)(v >> 32), l);
    return ((uint64_t)hi << 32) | lo;
}

// Exact replacement for RN(inter/den) > 0.7f (den > 0 always):
//   RN(q) > c  <=>  q >= M, M = c + 2^-25 (midpoint; tie rounds to even = c_next > c).
//   M has 25-bit significand, den 24 bits -> M*den exact in f64; comparison exact.
__device__ __forceinline__ uint32_t sup_bit(const float4 bi, float ai, const float4 bj, float aj) {
    float y1 = fmaxf(bi.x, bj.x), x1 = fmaxf(bi.y, bj.y);
    float y2 = fminf(bi.z, bj.z), x2 = fminf(bi.w, bj.w);
    float inter = __fmul_rn(fmaxf(__fsub_rn(y2, y1), 0.f), fmaxf(__fsub_rn(x2, x1), 0.f));
    float den = __fadd_rn(__fsub_rn(__fadd_rn(ai, aj), inter), 1e-10f);
    const double MSUP = 23488103.0 / 33554432.0;   // 0.7f + 2^-25, exact
    return (double)inter >= MSUP * (double)den;
}

__device__ __forceinline__ uint32_t score_bin(float sc) {
    uint32_t u = (uint32_t)(sc * 16777216.0f);
    u = u > 16777215u ? 16777215u : u;
    return u >> 16;
}

// ---------- K1: per-block LDS histogram -> global 256-bin per-batch hist ----------
__global__ void k_hist(const float4* __restrict__ probs, uint32_t* __restrict__ ghist) {
    __shared__ uint32_t lh[256];
    int blk = blockIdx.x;
    int b = blk >> 6;
    int t = threadIdx.x;
    lh[t] = 0u;
    __syncthreads();
    size_t fbase = ((size_t)b * (NN / 2)) + (size_t)(blk & 63) * 2048;
#pragma unroll
    for (int k = 0; k < 8; ++k) {
        float4 v = probs[fbase + k * 256 + t];
        atomicAdd(&lh[score_bin(v.y)], 1u);
        atomicAdd(&lh[score_bin(v.w)], 1u);
    }
    __syncthreads();
    uint32_t c = lh[t];
    if (c) atomicAdd(&ghist[(b << 8) + t], c);
}

// ---------- K3: compact candidates (threshold derived in-block), block-aggregated ----------
__global__ void k_compact(const float4* __restrict__ probs, const uint32_t* __restrict__ ghist,
                          uint32_t* __restrict__ cnt, uint64_t* __restrict__ cand) {
    __shared__ uint64_t stage[STAGE_CAP];
    __shared__ uint32_t lh[256];
    __shared__ uint32_t s_bst, lcnt, lbase;
    int blk = blockIdx.x;
    int b = blk >> 6;
    int t = threadIdx.x;
    lh[t] = ghist[(b << 8) + t];
    if (t == 0) lcnt = 0u;
    __syncthreads();
    if (t == 0) {
        uint32_t cum = 0; uint32_t bst = 0;
        for (int c = 255; c >= 0; --c) {
            cum += lh[c];
            if (cum >= (uint32_t)KSEL) { bst = (uint32_t)c; break; }
        }
        s_bst = bst;
    }
    __syncthreads();
    uint32_t bst = s_bst;
    int ibase = (blk & 63) * 4096;
    size_t fbase = ((size_t)b * (NN / 2)) + (size_t)(blk & 63) * 2048;
#pragma unroll
    for (int k = 0; k < 8; ++k) {
        float4 v = probs[fbase + k * 256 + t];
        int i0 = ibase + (k * 256 + t) * 2;
#pragma unroll
        for (int e = 0; e < 2; ++e) {
            float sc = e ? v.w : v.y;
            if (score_bin(sc) >= bst) {
                uint32_t p = atomicAdd(&lcnt, 1u);
                if (p < STAGE_CAP) {
                    uint32_t bits = __float_as_uint(sc);
                    stage[p] = ((uint64_t)bits << 32) | (uint32_t)(~(uint32_t)(i0 + e));
                }
            }
        }
    }
    __syncthreads();
    if (t == 0) {
        uint32_t m = lcnt > STAGE_CAP ? STAGE_CAP : lcnt;
        lbase = atomicAdd(&cnt[b], m);
        lcnt = m;
    }
    __syncthreads();
    uint32_t m = lcnt, base = lbase;
    for (uint32_t s = t; s < m; s += 256) {
        uint32_t pos = base + s;
        if (pos < CAND_CAP) cand[((uint64_t)b << 13) + pos] = stage[s];
    }
}

// ---------- K4a: bitonic phase A — sort each 1024-chunk DESCENDING (local dir) ----------
__launch_bounds__(512)
__global__ void k_sort1(const uint32_t* __restrict__ cnt, uint64_t* __restrict__ cand) {
    __shared__ uint64_t key[1024];
    int b = blockIdx.y, ch = blockIdx.x, t = threadIdx.x;
    uint32_t M = cnt[b]; if (M > CAND_CAP) M = CAND_CAP;
    uint64_t* cb = cand + ((uint64_t)b << 13);
    int base = ch << 10;
    for (int i = t; i < 1024; i += 512) key[i] = ((uint32_t)(base + i) < M) ? cb[base + i] : 0ull;
    __syncthreads();
    for (int kk = 2; kk <= 1024; kk <<= 1) {
        for (int j = kk >> 1; j > 0; j >>= 1) {
            for (int e = t; e < 1024; e += 512) {
                int ixj = e ^ j;
                if (ixj > e) {
                    uint64_t a = key[e], c = key[ixj];
                    bool ddd = ((e & kk) == 0);            // local direction: descending chunk
                    if ((a < c) == ddd) { key[e] = c; key[ixj] = a; }
                }
            }
            __syncthreads();
        }
    }
    for (int i = t; i < 1024; i += 512) cb[base + i] = key[i];
}

// ---------- K4b: merge-path level — merge descending runs of length R into 2R ----------
__launch_bounds__(256)
__global__ void k_merge(int R, const uint64_t* __restrict__ src, uint64_t* __restrict__ dst) {
    int b = blockIdx.y;
    int k = (blockIdx.x << 8) + threadIdx.x;        // [0, 8192)
    const uint64_t* base = src + ((uint64_t)b << 13);
    int run = k / (2 * R);
    int ko = k - run * (2 * R);                     // rank within merged run
    const uint64_t* A = base + (size_t)run * 2 * R;
    const uint64_t* B = A + R;
    int lo = ko - R; if (lo < 0) lo = 0;
    int hi = ko < R ? ko : R;
    while (lo < hi) {
        int m = (lo + hi) >> 1;
        int t = ko - m - 1;
        uint64_t bv = (t < 0) ? ~0ull : (t >= R ? 0ull : B[t]);
        if (A[m] > bv) lo = m + 1; else hi = m;     // A[m] comes before rank ko
    }
    int i = lo, j = ko - lo;
    uint64_t av = (i >= R) ? 0ull : A[i];
    uint64_t bv = (j >= R) ? 0ull : B[j];
    dst[((uint64_t)b << 13) + k] = (av > bv) ? av : bv;
}

// ---------- K4c: gather + decode (wide: 6 blocks x 1024 per batch) ----------
__launch_bounds__(1024)
__global__ void k_decode(const uint64_t* __restrict__ keys,
                         const float4* __restrict__ rpn_bbox, const float4* __restrict__ anchors,
                         float4* __restrict__ boxes, float* __restrict__ scoresS,
                         float* __restrict__ areas) {
    int b = blockIdx.y;
    int r = (blockIdx.x << 10) + threadIdx.x;       // [0, 6144)
    float4 bx = make_float4(0.f, 0.f, 0.f, 0.f);
    float sc = 0.f, ar = 0.f;
    if (r < KSEL) {
        uint64_t k64 = keys[((uint64_t)b << 13) + r];
        uint32_t idx = ~(uint32_t)(k64 & 0xFFFFFFFFull);
        sc = __uint_as_float((uint32_t)(k64 >> 32));
        size_t off = ((size_t)b << 18) + idx;
        float4 a = anchors[off];
        float4 d4 = rpn_bbox[off];
        float d0 = __fmul_rn(d4.x, 0.1f), d1 = __fmul_rn(d4.y, 0.1f);
        float d2 = __fmul_rn(d4.z, 0.2f), d3 = __fmul_rn(d4.w, 0.2f);
        float h = __fsub_rn(a.z, a.x), w = __fsub_rn(a.w, a.y);
        float cy = __fadd_rn(__fadd_rn(a.x, __fmul_rn(0.5f, h)), __fmul_rn(d0, h));
        float cx = __fadd_rn(__fadd_rn(a.y, __fmul_rn(0.5f, w)), __fmul_rn(d1, w));
        float h2 = __fmul_rn(h, expf(d2));
        float w2 = __fmul_rn(w, expf(d3));
        float y1 = __fsub_rn(cy, __fmul_rn(0.5f, h2));
        float x1 = __fsub_rn(cx, __fmul_rn(0.5f, w2));
        float y2 = __fadd_rn(cy, __fmul_rn(0.5f, h2));
        float x2 = __fadd_rn(cx, __fmul_rn(0.5f, w2));
        y1 = fminf(fmaxf(y1, 0.f), 1.f); x1 = fminf(fmaxf(x1, 0.f), 1.f);
        y2 = fminf(fmaxf(y2, 0.f), 1.f); x2 = fminf(fmaxf(x2, 0.f), 1.f);
        bx = make_float4(y1, x1, y2, x2);
        ar = __fmul_rn(__fsub_rn(y2, y1), __fsub_rn(x2, x1));
    }
    boxes[b * KPAD2 + r] = bx;
    scoresS[b * KPAD2 + r] = sc;
    areas[b * KPAD2 + r] = ar;
}

// ---------- K5: suppression bit rows for a word-chunk [w0, ...), 2 rows/thread ----------
__launch_bounds__(128)
__global__ void k_matc(int w0, const float4* __restrict__ boxes, const float* __restrict__ areas,
                       uint64_t* __restrict__ mat, uint64_t* __restrict__ diag,
                       const uint32_t* __restrict__ done) {
    int b = blockIdx.y;
    if (done[b]) return;
    int q = blockIdx.x, W = w0;
    while (q >= W + 1) { q -= W + 1; ++W; }
    int sub = q;                          // [0, W]
    int ibase = sub << 8;
    int t = threadIdx.x;
    __shared__ float4 sb[256];
    __shared__ float sa[256];
    size_t bb = (size_t)b * KPAD2;
    int j0 = W << 8;
    sb[t] = boxes[bb + j0 + t];
    sb[t + 128] = boxes[bb + j0 + t + 128];
    sa[t] = areas[bb + j0 + t];
    sa[t + 128] = areas[bb + j0 + t + 128];
    __syncthreads();
    int iA = ibase + t, iB = ibase + t + 128;
    float4 bA = boxes[bb + iA], bB = boxes[bb + iB];
    float aA = areas[bb + iA], aB = areas[bb + iB];
    uint32_t accA[8] = {0, 0, 0, 0, 0, 0, 0, 0};
    uint32_t accB[8] = {0, 0, 0, 0, 0, 0, 0, 0};
#pragma unroll 4
    for (int jj = 0; jj < 32; ++jj) {
#pragma unroll
        for (int s = 0; s < 4; ++s) {
            int j = (s << 6) + jj;
            float4 bj = sb[j]; float aj = sa[j];
            accA[s * 2] |= sup_bit(bA, aA, bj, aj) << jj;
            accB[s * 2] |= sup_bit(bB, aB, bj, aj) << jj;
        }
    }
#pragma unroll 4
    for (int jj = 32; jj < 64; ++jj) {
#pragma unroll
        for (int s = 0; s < 4; ++s) {
            int j = (s << 6) + jj;
            float4 bj = sb[j]; float aj = sa[j];
            accA[s * 2 + 1] |= sup_bit(bA, aA, bj, aj) << (jj - 32);
            accB[s * 2 + 1] |= sup_bit(bB, aB, bj, aj) << (jj - 32);
        }
    }
    uint64_t* rowA;
    uint64_t* rowB;
    if (sub == W) {
        uint64_t dbase = (uint64_t)b * DIAG_U64_PB;
        rowA = diag + dbase + (uint64_t)(j0 + t) * 4;
        rowB = diag + dbase + (uint64_t)(j0 + t + 128) * 4;
    } else {
        uint64_t mbase = (uint64_t)b * MAT_U64_PB + 512ull * W * (W - 1);
        rowA = mat + mbase + (uint64_t)iA * 4;
        rowB = mat + mbase + (uint64_t)iB * 4;
    }
    ulonglong2 vA0, vA1, vB0, vB1;
    vA0.x = (uint64_t)accA[0] | ((uint64_t)accA[1] << 32);
    vA0.y = (uint64_t)accA[2] | ((uint64_t)accA[3] << 32);
    vA1.x = (uint64_t)accA[4] | ((uint64_t)accA[5] << 32);
    vA1.y = (uint64_t)accA[6] | ((uint64_t)accA[7] << 32);
    vB0.x = (uint64_t)accB[0] | ((uint64_t)accB[1] << 32);
    vB0.y = (uint64_t)accB[2] | ((uint64_t)accB[3] << 32);
    vB1.x = (uint64_t)accB[4] | ((uint64_t)accB[5] << 32);
    vB1.y = (uint64_t)accB[6] | ((uint64_t)accB[7] << 32);
    ((ulonglong2*)rowA)[0] = vA0; ((ulonglong2*)rowA)[1] = vA1;
    ((ulonglong2*)rowB)[0] = vB0; ((ulonglong2*)rowB)[1] = vB1;
}

// ---------- K6: greedy NMS over words [w0,w1); bulk-pick (first-suppressor) ----------
__launch_bounds__(256)
__global__ void k_nms_chunk(int w0, int w1, int final_chunk,
                            const float4* __restrict__ boxes, const float* __restrict__ scoresS,
                            const uint64_t* __restrict__ diag, const uint64_t* __restrict__ mat,
                            uint32_t* __restrict__ gsel, uint32_t* __restrict__ ncount,
                            uint32_t* __restrict__ done, float* __restrict__ out) {
    __shared__ uint32_t sel[PROP];           // 4 KB (global indices)
    __shared__ uint64_t diagrow[256][4];     // 8 KB
    __shared__ uint32_t suppw[8];
    __shared__ uint32_t s_count;

    int b = blockIdx.x;
    if (done[b]) return;
    int tid = threadIdx.x;
    int wid = tid >> 6, lane = tid & 63;
    size_t bb = (size_t)b * KPAD2;
    const uint64_t* mb = mat + (uint64_t)b * MAT_U64_PB;
    const uint64_t* dgb = diag + (uint64_t)b * DIAG_U64_PB;
    uint32_t* gs = gsel + b * 1024;

    int count = (int)ncount[b];
    for (int r = tid; r < count; r += 256) sel[r] = gs[r];
    __syncthreads();

    for (int W = w0; W < w1; ++W) {
        // stage diag rows of word W into LDS; zero suppw
        {
            const ulonglong2* src = (const ulonglong2*)(dgb + (uint64_t)(W << 8) * 4);
            ulonglong2* dst = (ulonglong2*)&diagrow[0][0];
            dst[tid * 2] = src[tid * 2];
            dst[tid * 2 + 1] = src[tid * 2 + 1];
        }
        if (tid < 8) suppw[tid] = 0u;
        __syncthreads();
        // crossing gather: rows of prior selections vs word W (4 slots/thread)
        uint64_t acc0 = 0, acc1 = 0, acc2 = 0, acc3 = 0;
        {
            const uint64_t* col = mb + 512ull * W * (W - 1);
            uint32_t c = (uint32_t)count;
            uint32_t i0 = tid, i1 = tid + 256, i2 = tid + 512, i3 = tid + 768;
            if (i0 < c) { const ulonglong2* r = (const ulonglong2*)(col + 4u * sel[i0]);
                          ulonglong2 x = r[0], y = r[1];
                          acc0 |= x.x; acc1 |= x.y; acc2 |= y.x; acc3 |= y.y; }
            if (i1 < c) { const ulonglong2* r = (const ulonglong2*)(col + 4u * sel[i1]);
                          ulonglong2 x = r[0], y = r[1];
                          acc0 |= x.x; acc1 |= x.y; acc2 |= y.x; acc3 |= y.y; }
            if (i2 < c) { const ulonglong2* r = (const ulonglong2*)(col + 4u * sel[i2]);
                          ulonglong2 x = r[0], y = r[1];
                          acc0 |= x.x; acc1 |= x.y; acc2 |= y.x; acc3 |= y.y; }
            if (i3 < c) { const ulonglong2* r = (const ulonglong2*)(col + 4u * sel[i3]);
                          ulonglong2 x = r[0], y = r[1];
                          acc0 |= x.x; acc1 |= x.y; acc2 |= y.x; acc3 |= y.y; }
        }
#pragma unroll
        for (int off = 32; off; off >>= 1) {
            acc0 |= shfl_xor_u64(acc0, off);
            acc1 |= shfl_xor_u64(acc1, off);
            acc2 |= shfl_xor_u64(acc2, off);
            acc3 |= shfl_xor_u64(acc3, off);
        }
        if (lane == 0) {
            if (acc0) { atomicOr(&suppw[0], (uint32_t)acc0); atomicOr(&suppw[1], (uint32_t)(acc0 >> 32)); }
            if (acc1) { atomicOr(&suppw[2], (uint32_t)acc1); atomicOr(&suppw[3], (uint32_t)(acc1 >> 32)); }
            if (acc2) { atomicOr(&suppw[4], (uint32_t)acc2); atomicOr(&suppw[5], (uint32_t)(acc2 >> 32)); }
            if (acc3) { atomicOr(&suppw[6], (uint32_t)acc3); atomicOr(&suppw[7], (uint32_t)(acc3 >> 32)); }
        }
        __syncthreads();
        int count_old = count;
        // wave 0: bulk greedy selection. Per subword, one ballot finds the first
        // box that suppresses any LATER alive box; all alive boxes up to and
        // including it are picked at once (exactly the greedy result: if an
        // alive pair (y<x) conflicted, y would be flagged and the run stops
        // at or before y). Only the suppressor's row is applied.
        if (wid == 0) {
            uint64_t a0 = ~(((uint64_t)suppw[1] << 32) | suppw[0]);
            uint64_t a1 = ~(((uint64_t)suppw[3] << 32) | suppw[2]);
            uint64_t a2 = ~(((uint64_t)suppw[5] << 32) | suppw[4]);
            uint64_t a3 = ~(((uint64_t)suppw[7] << 32) | suppw[6]);
            if (W == NW2 - 1) { a1 &= (1ull << 48) - 1; a2 = 0; a3 = 0; }   // j < 6000 valid
            uint64_t pk0 = 0, pk1 = 0, pk2 = 0, pk3 = 0;
            uint64_t hi_mask = (lane == 63) ? 0ull : (~0ull << (lane + 1));

#define SUBP(S, AS, PK)                                                       \
            if (AS && count < PROP) {                                         \
                uint64_t own = diagrow[(S << 6) + lane][S];                   \
                while (AS && count < PROP) {                                  \
                    uint32_t alive_l = (uint32_t)((AS >> lane) & 1ull);       \
                    uint64_t inter = own & AS & hi_mask;                      \
                    unsigned long long conf = __ballot(alive_l && (inter != 0ull)); \
                    uint64_t run, rowc = 0ull;                                \
                    if (conf == 0ull) { run = AS; }                           \
                    else {                                                    \
                        uint32_t c = (uint32_t)__builtin_ctzll(conf);         \
                        uint64_t lo = ((1ull << c) << 1) - 1ull;              \
                        run = AS & lo;                                        \
                        rowc = rdlane64(own, c);                              \
                    }                                                         \
                    int pr = (int)__popcll(run);                              \
                    if (count + pr > PROP) {                                  \
                        int need = PROP - count;                              \
                        while (need-- > 0) {                                  \
                            uint32_t bp = (uint32_t)__builtin_ctzll(run);     \
                            PK |= 1ull << bp;                                 \
                            run &= run - 1ull;                                \
                        }                                                     \
                        count = PROP; AS = 0ull;                              \
                    } else {                                                  \
                        PK |= run; count += pr;                               \
                        AS &= ~run; AS &= ~rowc;                              \
                    }                                                         \
                }                                                             \
            }
            SUBP(0, a0, pk0)
            // transition: picked subword-0 boxes suppress subwords 1..3
            if (pk0 && count < PROP) {
                uint32_t pl = (uint32_t)((pk0 >> lane) & 1ull);
                uint64_t x1 = pl ? diagrow[lane][1] : 0ull;
                uint64_t x2 = pl ? diagrow[lane][2] : 0ull;
                uint64_t x3 = pl ? diagrow[lane][3] : 0ull;
#pragma unroll
                for (int off = 32; off; off >>= 1) {
                    x1 |= shfl_xor_u64(x1, off);
                    x2 |= shfl_xor_u64(x2, off);
                    x3 |= shfl_xor_u64(x3, off);
                }
                a1 &= ~rdfl64(x1); a2 &= ~rdfl64(x2); a3 &= ~rdfl64(x3);
            }
            SUBP(1, a1, pk1)
            if (pk1 && count < PROP) {
                uint32_t pl = (uint32_t)((pk1 >> lane) & 1ull);
                uint64_t x2 = pl ? diagrow[64 + lane][2] : 0ull;
                uint64_t x3 = pl ? diagrow[64 + lane][3] : 0ull;
#pragma unroll
                for (int off = 32; off; off >>= 1) {
                    x2 |= shfl_xor_u64(x2, off);
                    x3 |= shfl_xor_u64(x3, off);
                }
                a2 &= ~rdfl64(x2); a3 &= ~rdfl64(x3);
            }
            SUBP(2, a2, pk2)
            if (pk2 && count < PROP) {
                uint32_t pl = (uint32_t)((pk2 >> lane) & 1ull);
                uint64_t x3 = pl ? diagrow[128 + lane][3] : 0ull;
#pragma unroll
                for (int off = 32; off; off >>= 1) x3 |= shfl_xor_u64(x3, off);
                a3 &= ~rdfl64(x3);
            }
            SUBP(3, a3, pk3)
#undef SUBP
            // parallel append: picks were made in ascending (S, bp) order
            uint32_t nb = (uint32_t)count_old;
#define APPEND(S, PK) {                                                       \
            if (PK) {                                                         \
                uint32_t my = (uint32_t)((PK >> lane) & 1ull);                \
                uint32_t rank = (uint32_t)__popcll(PK & ((1ull << lane) - 1ull));\
                if (my) {                                                     \
                    uint32_t v = (uint32_t)((W << 8) + (S << 6) + lane);      \
                    sel[nb + rank] = v;                                       \
                    gs[nb + rank] = v;                                        \
                }                                                             \
                nb += (uint32_t)__popcll(PK);                                 \
            } }
            APPEND(0, pk0)
            APPEND(1, pk1)
            APPEND(2, pk2)
            APPEND(3, pk3)
#undef APPEND
            if (lane == 0) s_count = (uint32_t)count;
        }
        __syncthreads();
        count = (int)s_count;
        if (count >= PROP) break;
    }

    if (count >= PROP || final_chunk) {
        if (tid == 0) { done[b] = 1u; ncount[b] = (uint32_t)count; }
        float* prop = out + b * (PROP * 4);
        float* psc = out + BB * PROP * 4 + b * PROP;
        for (int r = tid; r < PROP; r += 256) {
            if (r < count) {
                uint32_t j = sel[r];
                float4 bx = boxes[bb + j];
                *(float4*)(prop + r * 4) = bx;
                psc[r] = scoresS[bb + j];
            } else {
                *(float4*)(prop + r * 4) = make_float4(0.f, 0.f, 0.f, 0.f);
                psc[r] = 0.f;
            }
        }
    } else {
        if (tid == 0) ncount[b] = (uint32_t)count;
    }
}

extern "C" void kernel_launch(void* const* d_in, const int* in_sizes, int n_in,
                              void* d_out, int out_size, void* d_ws, size_t ws_size,
                              hipStream_t stream) {
    const float4* probs = (const float4*)d_in[0];
    const float4* rpn_bbox = (const float4*)d_in[1];
    const float4* anchors = (const float4*)d_in[2];
    float* out = (float*)d_out;

    uint8_t* p = (uint8_t*)d_ws;
    size_t off = 0;
    auto alloc = [&](size_t bytes) -> void* {
        void* q = p + off;
        off += (bytes + 255) & ~(size_t)255;
        return q;
    };
    uint32_t* ghist = (uint32_t*)alloc((size_t)BB * 256 * 4);              // 8 KB
    uint32_t* cnt = (uint32_t*)alloc(BB * 4);
    uint32_t* ncount = (uint32_t*)alloc(BB * 4);
    uint32_t* ndone = (uint32_t*)alloc(BB * 4);
    uint64_t* cand = (uint64_t*)alloc((size_t)BB * CAND_CAP * 8);          // 512 KB
    uint64_t* cand2 = (uint64_t*)alloc((size_t)BB * CAND_CAP * 8);         // 512 KB
    float4* boxes = (float4*)alloc((size_t)BB * KPAD2 * 16);               // 768 KB
    float* scoresS = (float*)alloc((size_t)BB * KPAD2 * 4);
    float* areas = (float*)alloc((size_t)BB * KPAD2 * 4);
    uint32_t* gsel = (uint32_t*)alloc((size_t)BB * 1024 * 4);              // 32 KB
    uint64_t* diag = (uint64_t*)alloc((size_t)BB * DIAG_U64_PB * 8);       // 1.57 MB
    uint64_t* mat = (uint64_t*)alloc((size_t)BB * MAT_U64_PB * 8);         // 18.1 MB

    if (off > ws_size) {
        hipMemsetAsync(d_out, 0, (size_t)out_size * 4, stream);
        return;
    }

    // zero ghist + cnt + ncount + ndone every call (contiguous leading region)
    hipMemsetAsync(ghist, 0, (size_t)BB * 256 * 4 + 3 * 256, stream);

    k_hist<<<BB * BPB, 256, 0, stream>>>(probs, ghist);
    k_compact<<<BB * BPB, 256, 0, stream>>>(probs, ghist, cnt, cand);
    dim3 gs1(8, BB);
    k_sort1<<<gs1, 512, 0, stream>>>(cnt, cand);
    dim3 gmg(32, BB);
    k_merge<<<gmg, 256, 0, stream>>>(1024, cand, cand2);
    k_merge<<<gmg, 256, 0, stream>>>(2048, cand2, cand);
    k_merge<<<gmg, 256, 0, stream>>>(4096, cand, cand2);
    dim3 gdc(6, BB);
    k_decode<<<gdc, 1024, 0, stream>>>(cand2, rpn_bbox, anchors, boxes, scoresS, areas);

    const int cb[5] = {0, 3, 6, 12, 24};
    for (int c = 0; c < 4; ++c) {
        int w0 = cb[c], w1 = cb[c + 1];
        int nblk = 0;
        for (int W = w0; W < w1; ++W) nblk += W + 1;
        dim3 gm(nblk, BB);
        k_matc<<<gm, 128, 0, stream>>>(w0, boxes, areas, mat, diag, ndone);
        k_nms_chunk<<<BB, 256, 0, stream>>>(w0, w1, (w1 == NW2) ? 1 : 0,
                                            boxes, scoresS, diag, mat,
                                            gsel, ncount, ndone, out);
    }
}

// Round 13
// 111.791 us; speedup vs baseline: 3.0964x; 1.2904x over previous
//
#include <hip/hip_runtime.h>
#include <stdint.h>

#define BB 8
#define NN 262144
#define KSEL 6000
#define KPAD2 6144
#define NW2 24               // 24 words of 256 boxes
#define PROP 1000
#define NMS_THR 0.7f
#define CAND_CAP 8192
#define BPB 64               // blocks per batch for hist/compact (4096 items each)
#define STAGE_CAP 768
#define MAT_U64_PB 282624ull // sum_{W=1..23} 256*W rows * 4 u64 = 512*23*24
#define DIAG_U64_PB 24576ull // 24*256*4

// ---------- helpers ----------
__device__ __forceinline__ unsigned long long shfl_xor_u64(unsigned long long v, int m) {
    unsigned lo = (unsigned)v, hi = (unsigned)(v >> 32);
    lo = __shfl_xor(lo, m);
    hi = __shfl_xor(hi, m);
    return ((unsigned long long)hi << 32) | lo;
}
__device__ __forceinline__ uint64_t rdfl64(uint64_t v) {
    uint32_t lo = __builtin_amdgcn_readfirstlane((uint32_t)v);
    uint32_t hi = __builtin_amdgcn_readfirstlane((uint32_t)(v >> 32));
    return ((uint64_t)hi << 32) | lo;
}
__device__ __forceinline__ uint64_t rdlane64(uint64_t v, uint32_t l) {
    uint32_t lo = __builtin_amdgcn_readlane((uint32_t)v, l);
    uint32_t hi = __builtin_amdgcn_readlane((uint32_t)(v >> 32), l);
    return ((uint64_t)hi << 32) | lo;
}

// Exact replacement for RN(inter/den) > 0.7f (den > 0 always):
//   RN(q) > c  <=>  q >= M, M = c + 2^-25 (midpoint; tie rounds to even = c_next > c).
//   M has 25-bit significand, den 24 bits -> M*den exact in f64; comparison exact.
__device__ __forceinline__ uint32_t sup_bit(const float4 bi, float ai, const float4 bj, float aj) {
    float y1 = fmaxf(bi.x, bj.x), x1 = fmaxf(bi.y, bj.y);
    float y2 = fminf(bi.z, bj.z), x2 = fminf(bi.w, bj.w);
    float inter = __fmul_rn(fmaxf(__fsub_rn(y2, y1), 0.f), fmaxf(__fsub_rn(x2, x1), 0.f));
    float den = __fadd_rn(__fsub_rn(__fadd_rn(ai, aj), inter), 1e-10f);
    const double MSUP = 23488103.0 / 33554432.0;   // 0.7f + 2^-25, exact
    return (double)inter >= MSUP * (double)den;
}

__device__ __forceinline__ uint32_t score_bin(float sc) {
    uint32_t u = (uint32_t)(sc * 16777216.0f);
    u = u > 16777215u ? 16777215u : u;
    return u >> 16;
}

// ---------- K1: per-block LDS histogram -> global 256-bin per-batch hist ----------
__global__ void k_hist(const float4* __restrict__ probs, uint32_t* __restrict__ ghist) {
    __shared__ uint32_t lh[256];
    int blk = blockIdx.x;
    int b = blk >> 6;
    int t = threadIdx.x;
    lh[t] = 0u;
    __syncthreads();
    size_t fbase = ((size_t)b * (NN / 2)) + (size_t)(blk & 63) * 2048;
#pragma unroll
    for (int k = 0; k < 8; ++k) {
        float4 v = probs[fbase + k * 256 + t];
        atomicAdd(&lh[score_bin(v.y)], 1u);
        atomicAdd(&lh[score_bin(v.w)], 1u);
    }
    __syncthreads();
    uint32_t c = lh[t];
    if (c) atomicAdd(&ghist[(b << 8) + t], c);
}

// ---------- K3: compact candidates (threshold derived in-block), block-aggregated ----------
__global__ void k_compact(const float4* __restrict__ probs, const uint32_t* __restrict__ ghist,
                          uint32_t* __restrict__ cnt, uint64_t* __restrict__ cand) {
    __shared__ uint64_t stage[STAGE_CAP];
    __shared__ uint32_t lh[256];
    __shared__ uint32_t s_bst, lcnt, lbase;
    int blk = blockIdx.x;
    int b = blk >> 6;
    int t = threadIdx.x;
    lh[t] = ghist[(b << 8) + t];
    if (t == 0) lcnt = 0u;
    __syncthreads();
    if (t == 0) {
        uint32_t cum = 0; uint32_t bst = 0;
        for (int c = 255; c >= 0; --c) {
            cum += lh[c];
            if (cum >= (uint32_t)KSEL) { bst = (uint32_t)c; break; }
        }
        s_bst = bst;
    }
    __syncthreads();
    uint32_t bst = s_bst;
    int ibase = (blk & 63) * 4096;
    size_t fbase = ((size_t)b * (NN / 2)) + (size_t)(blk & 63) * 2048;
#pragma unroll
    for (int k = 0; k < 8; ++k) {
        float4 v = probs[fbase + k * 256 + t];
        int i0 = ibase + (k * 256 + t) * 2;
#pragma unroll
        for (int e = 0; e < 2; ++e) {
            float sc = e ? v.w : v.y;
            if (score_bin(sc) >= bst) {
                uint32_t p = atomicAdd(&lcnt, 1u);
                if (p < STAGE_CAP) {
                    uint32_t bits = __float_as_uint(sc);
                    stage[p] = ((uint64_t)bits << 32) | (uint32_t)(~(uint32_t)(i0 + e));
                }
            }
        }
    }
    __syncthreads();
    if (t == 0) {
        uint32_t m = lcnt > STAGE_CAP ? STAGE_CAP : lcnt;
        lbase = atomicAdd(&cnt[b], m);
        lcnt = m;
    }
    __syncthreads();
    uint32_t m = lcnt, base = lbase;
    for (uint32_t s = t; s < m; s += 256) {
        uint32_t pos = base + s;
        if (pos < CAND_CAP) cand[((uint64_t)b << 13) + pos] = stage[s];
    }
}

// ---------- K4a: bitonic phase A — sort each 1024-chunk DESCENDING (local dir) ----------
__launch_bounds__(512)
__global__ void k_sort1(const uint32_t* __restrict__ cnt, uint64_t* __restrict__ cand) {
    __shared__ uint64_t key[1024];
    int b = blockIdx.y, ch = blockIdx.x, t = threadIdx.x;
    uint32_t M = cnt[b]; if (M > CAND_CAP) M = CAND_CAP;
    uint64_t* cb = cand + ((uint64_t)b << 13);
    int base = ch << 10;
    for (int i = t; i < 1024; i += 512) key[i] = ((uint32_t)(base + i) < M) ? cb[base + i] : 0ull;
    __syncthreads();
    for (int kk = 2; kk <= 1024; kk <<= 1) {
        for (int j = kk >> 1; j > 0; j >>= 1) {
            for (int e = t; e < 1024; e += 512) {
                int ixj = e ^ j;
                if (ixj > e) {
                    uint64_t a = key[e], c = key[ixj];
                    bool ddd = ((e & kk) == 0);            // local direction: descending chunk
                    if ((a < c) == ddd) { key[e] = c; key[ixj] = a; }
                }
            }
            __syncthreads();
        }
    }
    for (int i = t; i < 1024; i += 512) cb[base + i] = key[i];
}

// ---------- K4b: merge-path level — merge descending runs of length R into 2R ----------
__launch_bounds__(256)
__global__ void k_merge(int R, const uint64_t* __restrict__ src, uint64_t* __restrict__ dst) {
    int b = blockIdx.y;
    int k = (blockIdx.x << 8) + threadIdx.x;        // [0, 8192)
    const uint64_t* base = src + ((uint64_t)b << 13);
    int run = k / (2 * R);
    int ko = k - run * (2 * R);                     // rank within merged run
    const uint64_t* A = base + (size_t)run * 2 * R;
    const uint64_t* B = A + R;
    int lo = ko - R; if (lo < 0) lo = 0;
    int hi = ko < R ? ko : R;
    while (lo < hi) {
        int m = (lo + hi) >> 1;
        int t = ko - m - 1;
        uint64_t bv = (t < 0) ? ~0ull : (t >= R ? 0ull : B[t]);
        if (A[m] > bv) lo = m + 1; else hi = m;     // A[m] comes before rank ko
    }
    int i = lo, j = ko - lo;
    uint64_t av = (i >= R) ? 0ull : A[i];
    uint64_t bv = (j >= R) ? 0ull : B[j];
    dst[((uint64_t)b << 13) + k] = (av > bv) ? av : bv;
}

// ---------- K4c: final merge level (R=4096) fused with gather+decode ----------
// Computes the final rank-k key via merge-path and decodes it directly; keys
// are never written back (nothing downstream needs them).
__launch_bounds__(256)
__global__ void k_merge_decode(const uint64_t* __restrict__ src,
                               const float4* __restrict__ rpn_bbox, const float4* __restrict__ anchors,
                               float4* __restrict__ boxes, float* __restrict__ scoresS,
                               float* __restrict__ areas) {
    const int R = 4096;
    int b = blockIdx.y;
    int k = (blockIdx.x << 8) + threadIdx.x;        // [0, 8192)
    if (k >= KPAD2) return;                         // only ranks < 6144 materialized
    const uint64_t* A = src + ((uint64_t)b << 13);
    const uint64_t* B = A + R;
    int lo = k - R; if (lo < 0) lo = 0;
    int hi = k < R ? k : R;
    while (lo < hi) {
        int m = (lo + hi) >> 1;
        int t = k - m - 1;
        uint64_t bv = (t < 0) ? ~0ull : (t >= R ? 0ull : B[t]);
        if (A[m] > bv) lo = m + 1; else hi = m;
    }
    int i = lo, j = k - lo;
    uint64_t av = (i >= R) ? 0ull : A[i];
    uint64_t bv = (j >= R) ? 0ull : B[j];
    uint64_t k64 = (av > bv) ? av : bv;

    float4 bx = make_float4(0.f, 0.f, 0.f, 0.f);
    float sc = 0.f, ar = 0.f;
    if (k < KSEL) {
        uint32_t idx = ~(uint32_t)(k64 & 0xFFFFFFFFull);
        sc = __uint_as_float((uint32_t)(k64 >> 32));
        size_t off = ((size_t)b << 18) + idx;
        float4 a = anchors[off];
        float4 d4 = rpn_bbox[off];
        float d0 = __fmul_rn(d4.x, 0.1f), d1 = __fmul_rn(d4.y, 0.1f);
        float d2 = __fmul_rn(d4.z, 0.2f), d3 = __fmul_rn(d4.w, 0.2f);
        float h = __fsub_rn(a.z, a.x), w = __fsub_rn(a.w, a.y);
        float cy = __fadd_rn(__fadd_rn(a.x, __fmul_rn(0.5f, h)), __fmul_rn(d0, h));
        float cx = __fadd_rn(__fadd_rn(a.y, __fmul_rn(0.5f, w)), __fmul_rn(d1, w));
        float h2 = __fmul_rn(h, expf(d2));
        float w2 = __fmul_rn(w, expf(d3));
        float y1 = __fsub_rn(cy, __fmul_rn(0.5f, h2));
        float x1 = __fsub_rn(cx, __fmul_rn(0.5f, w2));
        float y2 = __fadd_rn(cy, __fmul_rn(0.5f, h2));
        float x2 = __fadd_rn(cx, __fmul_rn(0.5f, w2));
        y1 = fminf(fmaxf(y1, 0.f), 1.f); x1 = fminf(fmaxf(x1, 0.f), 1.f);
        y2 = fminf(fmaxf(y2, 0.f), 1.f); x2 = fminf(fmaxf(x2, 0.f), 1.f);
        bx = make_float4(y1, x1, y2, x2);
        ar = __fmul_rn(__fsub_rn(y2, y1), __fsub_rn(x2, x1));
    }
    boxes[b * KPAD2 + k] = bx;
    scoresS[b * KPAD2 + k] = sc;
    areas[b * KPAD2 + k] = ar;
}

// ---------- K5: suppression bit rows for a word-chunk [w0, ...), 2 rows/thread ----------
__launch_bounds__(128)
__global__ void k_matc(int w0, const float4* __restrict__ boxes, const float* __restrict__ areas,
                       uint64_t* __restrict__ mat, uint64_t* __restrict__ diag,
                       const uint32_t* __restrict__ done) {
    int b = blockIdx.y;
    if (done[b]) return;
    int q = blockIdx.x, W = w0;
    while (q >= W + 1) { q -= W + 1; ++W; }
    int sub = q;                          // [0, W]
    int ibase = sub << 8;
    int t = threadIdx.x;
    __shared__ float4 sb[256];
    __shared__ float sa[256];
    size_t bb = (size_t)b * KPAD2;
    int j0 = W << 8;
    sb[t] = boxes[bb + j0 + t];
    sb[t + 128] = boxes[bb + j0 + t + 128];
    sa[t] = areas[bb + j0 + t];
    sa[t + 128] = areas[bb + j0 + t + 128];
    __syncthreads();
    int iA = ibase + t, iB = ibase + t + 128;
    float4 bA = boxes[bb + iA], bB = boxes[bb + iB];
    float aA = areas[bb + iA], aB = areas[bb + iB];
    uint32_t accA[8] = {0, 0, 0, 0, 0, 0, 0, 0};
    uint32_t accB[8] = {0, 0, 0, 0, 0, 0, 0, 0};
#pragma unroll 4
    for (int jj = 0; jj < 32; ++jj) {
#pragma unroll
        for (int s = 0; s < 4; ++s) {
            int j = (s << 6) + jj;
            float4 bj = sb[j]; float aj = sa[j];
            accA[s * 2] |= sup_bit(bA, aA, bj, aj) << jj;
            accB[s * 2] |= sup_bit(bB, aB, bj, aj) << jj;
        }
    }
#pragma unroll 4
    for (int jj = 32; jj < 64; ++jj) {
#pragma unroll
        for (int s = 0; s < 4; ++s) {
            int j = (s << 6) + jj;
            float4 bj = sb[j]; float aj = sa[j];
            accA[s * 2 + 1] |= sup_bit(bA, aA, bj, aj) << (jj - 32);
            accB[s * 2 + 1] |= sup_bit(bB, aB, bj, aj) << (jj - 32);
        }
    }
    uint64_t* rowA;
    uint64_t* rowB;
    if (sub == W) {
        uint64_t dbase = (uint64_t)b * DIAG_U64_PB;
        rowA = diag + dbase + (uint64_t)(j0 + t) * 4;
        rowB = diag + dbase + (uint64_t)(j0 + t + 128) * 4;
    } else {
        uint64_t mbase = (uint64_t)b * MAT_U64_PB + 512ull * W * (W - 1);
        rowA = mat + mbase + (uint64_t)iA * 4;
        rowB = mat + mbase + (uint64_t)iB * 4;
    }
    ulonglong2 vA0, vA1, vB0, vB1;
    vA0.x = (uint64_t)accA[0] | ((uint64_t)accA[1] << 32);
    vA0.y = (uint64_t)accA[2] | ((uint64_t)accA[3] << 32);
    vA1.x = (uint64_t)accA[4] | ((uint64_t)accA[5] << 32);
    vA1.y = (uint64_t)accA[6] | ((uint64_t)accA[7] << 32);
    vB0.x = (uint64_t)accB[0] | ((uint64_t)accB[1] << 32);
    vB0.y = (uint64_t)accB[2] | ((uint64_t)accB[3] << 32);
    vB1.x = (uint64_t)accB[4] | ((uint64_t)accB[5] << 32);
    vB1.y = (uint64_t)accB[6] | ((uint64_t)accB[7] << 32);
    ((ulonglong2*)rowA)[0] = vA0; ((ulonglong2*)rowA)[1] = vA1;
    ((ulonglong2*)rowB)[0] = vB0; ((ulonglong2*)rowB)[1] = vB1;
}

// ---------- K6: greedy NMS over words [w0,w1); bulk-pick (first-suppressor) ----------
__launch_bounds__(256)
__global__ void k_nms_chunk(int w0, int w1, int final_chunk,
                            const float4* __restrict__ boxes, const float* __restrict__ scoresS,
                            const uint64_t* __restrict__ diag, const uint64_t* __restrict__ mat,
                            uint32_t* __restrict__ gsel, uint32_t* __restrict__ ncount,
                            uint32_t* __restrict__ done, float* __restrict__ out) {
    __shared__ uint32_t sel[PROP];           // 4 KB (global indices)
    __shared__ uint64_t diagrow[256][4];     // 8 KB
    __shared__ uint32_t suppw[8];
    __shared__ uint32_t s_count;

    int b = blockIdx.x;
    if (done[b]) return;
    int tid = threadIdx.x;
    int wid = tid >> 6, lane = tid & 63;
    size_t bb = (size_t)b * KPAD2;
    const uint64_t* mb = mat + (uint64_t)b * MAT_U64_PB;
    const uint64_t* dgb = diag + (uint64_t)b * DIAG_U64_PB;
    uint32_t* gs = gsel + b * 1024;

    int count = (int)ncount[b];
    for (int r = tid; r < count; r += 256) sel[r] = gs[r];
    __syncthreads();

    for (int W = w0; W < w1; ++W) {
        // stage diag rows of word W into LDS; zero suppw
        {
            const ulonglong2* src = (const ulonglong2*)(dgb + (uint64_t)(W << 8) * 4);
            ulonglong2* dst = (ulonglong2*)&diagrow[0][0];
            dst[tid * 2] = src[tid * 2];
            dst[tid * 2 + 1] = src[tid * 2 + 1];
        }
        if (tid < 8) suppw[tid] = 0u;
        __syncthreads();
        // crossing gather: rows of prior selections vs word W (4 slots/thread)
        uint64_t acc0 = 0, acc1 = 0, acc2 = 0, acc3 = 0;
        {
            const uint64_t* col = mb + 512ull * W * (W - 1);
            uint32_t c = (uint32_t)count;
            uint32_t i0 = tid, i1 = tid + 256, i2 = tid + 512, i3 = tid + 768;
            if (i0 < c) { const ulonglong2* r = (const ulonglong2*)(col + 4u * sel[i0]);
                          ulonglong2 x = r[0], y = r[1];
                          acc0 |= x.x; acc1 |= x.y; acc2 |= y.x; acc3 |= y.y; }
            if (i1 < c) { const ulonglong2* r = (const ulonglong2*)(col + 4u * sel[i1]);
                          ulonglong2 x = r[0], y = r[1];
                          acc0 |= x.x; acc1 |= x.y; acc2 |= y.x; acc3 |= y.y; }
            if (i2 < c) { const ulonglong2* r = (const ulonglong2*)(col + 4u * sel[i2]);
                          ulonglong2 x = r[0], y = r[1];
                          acc0 |= x.x; acc1 |= x.y; acc2 |= y.x; acc3 |= y.y; }
            if (i3 < c) { const ulonglong2* r = (const ulonglong2*)(col + 4u * sel[i3]);
                          ulonglong2 x = r[0], y = r[1];
                          acc0 |= x.x; acc1 |= x.y; acc2 |= y.x; acc3 |= y.y; }
        }
#pragma unroll
        for (int off = 32; off; off >>= 1) {
            acc0 |= shfl_xor_u64(acc0, off);
            acc1 |= shfl_xor_u64(acc1, off);
            acc2 |= shfl_xor_u64(acc2, off);
            acc3 |= shfl_xor_u64(acc3, off);
        }
        if (lane == 0) {
            if (acc0) { atomicOr(&suppw[0], (uint32_t)acc0); atomicOr(&suppw[1], (uint32_t)(acc0 >> 32)); }
            if (acc1) { atomicOr(&suppw[2], (uint32_t)acc1); atomicOr(&suppw[3], (uint32_t)(acc1 >> 32)); }
            if (acc2) { atomicOr(&suppw[4], (uint32_t)acc2); atomicOr(&suppw[5], (uint32_t)(acc2 >> 32)); }
            if (acc3) { atomicOr(&suppw[6], (uint32_t)acc3); atomicOr(&suppw[7], (uint32_t)(acc3 >> 32)); }
        }
        __syncthreads();
        int count_old = count;
        // wave 0: bulk greedy selection (first-suppressor batching; proven r12)
        if (wid == 0) {
            uint64_t a0 = ~(((uint64_t)suppw[1] << 32) | suppw[0]);
            uint64_t a1 = ~(((uint64_t)suppw[3] << 32) | suppw[2]);
            uint64_t a2 = ~(((uint64_t)suppw[5] << 32) | suppw[4]);
            uint64_t a3 = ~(((uint64_t)suppw[7] << 32) | suppw[6]);
            if (W == NW2 - 1) { a1 &= (1ull << 48) - 1; a2 = 0; a3 = 0; }   // j < 6000 valid
            uint64_t pk0 = 0, pk1 = 0, pk2 = 0, pk3 = 0;
            uint64_t hi_mask = (lane == 63) ? 0ull : (~0ull << (lane + 1));

#define SUBP(S, AS, PK)                                                       \
            if (AS && count < PROP) {                                         \
                uint64_t own = diagrow[(S << 6) + lane][S];                   \
                while (AS && count < PROP) {                                  \
                    uint32_t alive_l = (uint32_t)((AS >> lane) & 1ull);       \
                    uint64_t inter = own & AS & hi_mask;                      \
                    unsigned long long conf = __ballot(alive_l && (inter != 0ull)); \
                    uint64_t run, rowc = 0ull;                                \
                    if (conf == 0ull) { run = AS; }                           \
                    else {                                                    \
                        uint32_t c = (uint32_t)__builtin_ctzll(conf);         \
                        uint64_t lo = ((1ull << c) << 1) - 1ull;              \
                        run = AS & lo;                                        \
                        rowc = rdlane64(own, c);                              \
                    }                                                         \
                    int pr = (int)__popcll(run);                              \
                    if (count + pr > PROP) {                                  \
                        int need = PROP - count;                              \
                        while (need-- > 0) {                                  \
                            uint32_t bp = (uint32_t)__builtin_ctzll(run);     \
                            PK |= 1ull << bp;                                 \
                            run &= run - 1ull;                                \
                        }                                                     \
                        count = PROP; AS = 0ull;                              \
                    } else {                                                  \
                        PK |= run; count += pr;                               \
                        AS &= ~run; AS &= ~rowc;                              \
                    }                                                         \
                }                                                             \
            }
            SUBP(0, a0, pk0)
            // transition: picked subword-0 boxes suppress subwords 1..3
            if (pk0 && count < PROP) {
                uint32_t pl = (uint32_t)((pk0 >> lane) & 1ull);
                uint64_t x1 = pl ? diagrow[lane][1] : 0ull;
                uint64_t x2 = pl ? diagrow[lane][2] : 0ull;
                uint64_t x3 = pl ? diagrow[lane][3] : 0ull;
#pragma unroll
                for (int off = 32; off; off >>= 1) {
                    x1 |= shfl_xor_u64(x1, off);
                    x2 |= shfl_xor_u64(x2, off);
                    x3 |= shfl_xor_u64(x3, off);
                }
                a1 &= ~rdfl64(x1); a2 &= ~rdfl64(x2); a3 &= ~rdfl64(x3);
            }
            SUBP(1, a1, pk1)
            if (pk1 && count < PROP) {
                uint32_t pl = (uint32_t)((pk1 >> lane) & 1ull);
                uint64_t x2 = pl ? diagrow[64 + lane][2] : 0ull;
                uint64_t x3 = pl ? diagrow[64 + lane][3] : 0ull;
#pragma unroll
                for (int off = 32; off; off >>= 1) {
                    x2 |= shfl_xor_u64(x2, off);
                    x3 |= shfl_xor_u64(x3, off);
                }
                a2 &= ~rdfl64(x2); a3 &= ~rdfl64(x3);
            }
            SUBP(2, a2, pk2)
            if (pk2 && count < PROP) {
                uint32_t pl = (uint32_t)((pk2 >> lane) & 1ull);
                uint64_t x3 = pl ? diagrow[128 + lane][3] : 0ull;
#pragma unroll
                for (int off = 32; off; off >>= 1) x3 |= shfl_xor_u64(x3, off);
                a3 &= ~rdfl64(x3);
            }
            SUBP(3, a3, pk3)
#undef SUBP
            // parallel append: picks were made in ascending (S, bp) order
            uint32_t nb = (uint32_t)count_old;
#define APPEND(S, PK) {                                                       \
            if (PK) {                                                         \
                uint32_t my = (uint32_t)((PK >> lane) & 1ull);                \
                uint32_t rank = (uint32_t)__popcll(PK & ((1ull << lane) - 1ull));\
                if (my) {                                                     \
                    uint32_t v = (uint32_t)((W << 8) + (S << 6) + lane);      \
                    sel[nb + rank] = v;                                       \
                    gs[nb + rank] = v;                                        \
                }                                                             \
                nb += (uint32_t)__popcll(PK);                                 \
            } }
            APPEND(0, pk0)
            APPEND(1, pk1)
            APPEND(2, pk2)
            APPEND(3, pk3)
#undef APPEND
            if (lane == 0) s_count = (uint32_t)count;
        }
        __syncthreads();
        count = (int)s_count;
        if (count >= PROP) break;
    }

    if (count >= PROP || final_chunk) {
        if (tid == 0) { done[b] = 1u; ncount[b] = (uint32_t)count; }
        float* prop = out + b * (PROP * 4);
        float* psc = out + BB * PROP * 4 + b * PROP;
        for (int r = tid; r < PROP; r += 256) {
            if (r < count) {
                uint32_t j = sel[r];
                float4 bx = boxes[bb + j];
                *(float4*)(prop + r * 4) = bx;
                psc[r] = scoresS[bb + j];
            } else {
                *(float4*)(prop + r * 4) = make_float4(0.f, 0.f, 0.f, 0.f);
                psc[r] = 0.f;
            }
        }
    } else {
        if (tid == 0) ncount[b] = (uint32_t)count;
    }
}

extern "C" void kernel_launch(void* const* d_in, const int* in_sizes, int n_in,
                              void* d_out, int out_size, void* d_ws, size_t ws_size,
                              hipStream_t stream) {
    const float4* probs = (const float4*)d_in[0];
    const float4* rpn_bbox = (const float4*)d_in[1];
    const float4* anchors = (const float4*)d_in[2];
    float* out = (float*)d_out;

    uint8_t* p = (uint8_t*)d_ws;
    size_t off = 0;
    auto alloc = [&](size_t bytes) -> void* {
        void* q = p + off;
        off += (bytes + 255) & ~(size_t)255;
        return q;
    };
    uint32_t* ghist = (uint32_t*)alloc((size_t)BB * 256 * 4);              // 8 KB
    uint32_t* cnt = (uint32_t*)alloc(BB * 4);
    uint32_t* ncount = (uint32_t*)alloc(BB * 4);
    uint32_t* ndone = (uint32_t*)alloc(BB * 4);
    uint64_t* cand = (uint64_t*)alloc((size_t)BB * CAND_CAP * 8);          // 512 KB
    uint64_t* cand2 = (uint64_t*)alloc((size_t)BB * CAND_CAP * 8);         // 512 KB
    float4* boxes = (float4*)alloc((size_t)BB * KPAD2 * 16);               // 768 KB
    float* scoresS = (float*)alloc((size_t)BB * KPAD2 * 4);
    float* areas = (float*)alloc((size_t)BB * KPAD2 * 4);
    uint32_t* gsel = (uint32_t*)alloc((size_t)BB * 1024 * 4);              // 32 KB
    uint64_t* diag = (uint64_t*)alloc((size_t)BB * DIAG_U64_PB * 8);       // 1.57 MB
    uint64_t* mat = (uint64_t*)alloc((size_t)BB * MAT_U64_PB * 8);         // 18.1 MB

    if (off > ws_size) {
        hipMemsetAsync(d_out, 0, (size_t)out_size * 4, stream);
        return;
    }

    // zero ghist + cnt + ncount + ndone every call (contiguous leading region)
    hipMemsetAsync(ghist, 0, (size_t)BB * 256 * 4 + 3 * 256, stream);

    k_hist<<<BB * BPB, 256, 0, stream>>>(probs, ghist);
    k_compact<<<BB * BPB, 256, 0, stream>>>(probs, ghist, cnt, cand);
    dim3 gs1(8, BB);
    k_sort1<<<gs1, 512, 0, stream>>>(cnt, cand);
    dim3 gmg(32, BB);
    k_merge<<<gmg, 256, 0, stream>>>(1024, cand, cand2);
    k_merge<<<gmg, 256, 0, stream>>>(2048, cand2, cand);
    dim3 gmd(24, BB);   // 24*256 = 6144 ranks materialized
    k_merge_decode<<<gmd, 256, 0, stream>>>(cand, rpn_bbox, anchors, boxes, scoresS, areas);

    const int cb[3] = {0, 6, 24};
    for (int c = 0; c < 2; ++c) {
        int w0 = cb[c], w1 = cb[c + 1];
        int nblk = 0;
        for (int W = w0; W < w1; ++W) nblk += W + 1;
        dim3 gm(nblk, BB);
        k_matc<<<gm, 128, 0, stream>>>(w0, boxes, areas, mat, diag, ndone);
        k_nms_chunk<<<BB, 256, 0, stream>>>(w0, w1, (w1 == NW2) ? 1 : 0,
                                            boxes, scoresS, diag, mat,
                                            gsel, ncount, ndone, out);
    }
}

// Round 14
// 111.230 us; speedup vs baseline: 3.1120x; 1.0050x over previous
//
#include <hip/hip_runtime.h>
#include <stdint.h>

#define BB 8
#define NN 262144
#define KSEL 6000
#define KPAD2 6144
#define NW2 24               // 24 words of 256 boxes
#define PROP 1000
#define NMS_THR 0.7f
#define CAND_CAP 8192
#define BPB 64               // blocks per batch for hist/compact (4096 items each)
#define STAGE_CAP 768
#define MAT_U64_PB 282624ull // sum_{W=1..23} 256*W rows * 4 u64 = 512*23*24
#define DIAG_U64_PB 24576ull // 24*256*4

// ---------- helpers ----------
__device__ __forceinline__ unsigned long long shfl_xor_u64(unsigned long long v, int m) {
    unsigned lo = (unsigned)v, hi = (unsigned)(v >> 32);
    lo = __shfl_xor(lo, m);
    hi = __shfl_xor(hi, m);
    return ((unsigned long long)hi << 32) | lo;
}
__device__ __forceinline__ uint64_t rdfl64(uint64_t v) {
    uint32_t lo = __builtin_amdgcn_readfirstlane((uint32_t)v);
    uint32_t hi = __builtin_amdgcn_readfirstlane((uint32_t)(v >> 32));
    return ((uint64_t)hi << 32) | lo;
}
__device__ __forceinline__ uint64_t rdlane64(uint64_t v, uint32_t l) {
    uint32_t lo = __builtin_amdgcn_readlane((uint32_t)v, l);
    uint32_t hi = __builtin_amdgcn_readlane((uint32_t)(v >> 32), l);
    return ((uint64_t)hi << 32) | lo;
}

// Exact replacement for RN(inter/den) > 0.7f (den > 0 always):
//   RN(q) > c  <=>  q >= M, M = c + 2^-25 (midpoint; tie rounds to even = c_next > c).
//   M has 25-bit significand, den 24 bits -> M*den exact in f64; comparison exact.
__device__ __forceinline__ uint32_t sup_bit(const float4 bi, float ai, const float4 bj, float aj) {
    float y1 = fmaxf(bi.x, bj.x), x1 = fmaxf(bi.y, bj.y);
    float y2 = fminf(bi.z, bj.z), x2 = fminf(bi.w, bj.w);
    float inter = __fmul_rn(fmaxf(__fsub_rn(y2, y1), 0.f), fmaxf(__fsub_rn(x2, x1), 0.f));
    float den = __fadd_rn(__fsub_rn(__fadd_rn(ai, aj), inter), 1e-10f);
    const double MSUP = 23488103.0 / 33554432.0;   // 0.7f + 2^-25, exact
    return (double)inter >= MSUP * (double)den;
}

__device__ __forceinline__ uint32_t score_bin(float sc) {
    uint32_t u = (uint32_t)(sc * 16777216.0f);
    u = u > 16777215u ? 16777215u : u;
    return u >> 16;
}

// ---------- K0: zero the small state (replaces pathological rocclr fill) ----------
__global__ void k_zero(uint32_t* __restrict__ ghist, uint32_t* __restrict__ cnt,
                       uint32_t* __restrict__ ncount, uint32_t* __restrict__ ndone) {
    int b = blockIdx.x, t = threadIdx.x;
    ghist[(b << 8) + t] = 0u;
    if (t == 0) { cnt[b] = 0u; ncount[b] = 0u; ndone[b] = 0u; }
}

// ---------- K1: per-block LDS histogram -> global 256-bin per-batch hist ----------
__global__ void k_hist(const float4* __restrict__ probs, uint32_t* __restrict__ ghist) {
    __shared__ uint32_t lh[256];
    int blk = blockIdx.x;
    int b = blk >> 6;
    int t = threadIdx.x;
    lh[t] = 0u;
    __syncthreads();
    size_t fbase = ((size_t)b * (NN / 2)) + (size_t)(blk & 63) * 2048;
#pragma unroll
    for (int k = 0; k < 8; ++k) {
        float4 v = probs[fbase + k * 256 + t];
        atomicAdd(&lh[score_bin(v.y)], 1u);
        atomicAdd(&lh[score_bin(v.w)], 1u);
    }
    __syncthreads();
    uint32_t c = lh[t];
    if (c) atomicAdd(&ghist[(b << 8) + t], c);
}

// ---------- K3: compact candidates (threshold derived in-block), block-aggregated ----------
__global__ void k_compact(const float4* __restrict__ probs, const uint32_t* __restrict__ ghist,
                          uint32_t* __restrict__ cnt, uint64_t* __restrict__ cand) {
    __shared__ uint64_t stage[STAGE_CAP];
    __shared__ uint32_t lh[256];
    __shared__ uint32_t s_bst, lcnt, lbase;
    int blk = blockIdx.x;
    int b = blk >> 6;
    int t = threadIdx.x;
    lh[t] = ghist[(b << 8) + t];
    if (t == 0) lcnt = 0u;
    __syncthreads();
    if (t == 0) {
        uint32_t cum = 0; uint32_t bst = 0;
        for (int c = 255; c >= 0; --c) {
            cum += lh[c];
            if (cum >= (uint32_t)KSEL) { bst = (uint32_t)c; break; }
        }
        s_bst = bst;
    }
    __syncthreads();
    uint32_t bst = s_bst;
    int ibase = (blk & 63) * 4096;
    size_t fbase = ((size_t)b * (NN / 2)) + (size_t)(blk & 63) * 2048;
#pragma unroll
    for (int k = 0; k < 8; ++k) {
        float4 v = probs[fbase + k * 256 + t];
        int i0 = ibase + (k * 256 + t) * 2;
#pragma unroll
        for (int e = 0; e < 2; ++e) {
            float sc = e ? v.w : v.y;
            if (score_bin(sc) >= bst) {
                uint32_t p = atomicAdd(&lcnt, 1u);
                if (p < STAGE_CAP) {
                    uint32_t bits = __float_as_uint(sc);
                    stage[p] = ((uint64_t)bits << 32) | (uint32_t)(~(uint32_t)(i0 + e));
                }
            }
        }
    }
    __syncthreads();
    if (t == 0) {
        uint32_t m = lcnt > STAGE_CAP ? STAGE_CAP : lcnt;
        lbase = atomicAdd(&cnt[b], m);
        lcnt = m;
    }
    __syncthreads();
    uint32_t m = lcnt, base = lbase;
    for (uint32_t s = t; s < m; s += 256) {
        uint32_t pos = base + s;
        if (pos < CAND_CAP) cand[((uint64_t)b << 13) + pos] = stage[s];
    }
}

// ---------- K4a: bitonic phase A — sort each 1024-chunk DESCENDING (local dir) ----------
__launch_bounds__(512)
__global__ void k_sort1(const uint32_t* __restrict__ cnt, uint64_t* __restrict__ cand) {
    __shared__ uint64_t key[1024];
    int b = blockIdx.y, ch = blockIdx.x, t = threadIdx.x;
    uint32_t M = cnt[b]; if (M > CAND_CAP) M = CAND_CAP;
    uint64_t* cb = cand + ((uint64_t)b << 13);
    int base = ch << 10;
    for (int i = t; i < 1024; i += 512) key[i] = ((uint32_t)(base + i) < M) ? cb[base + i] : 0ull;
    __syncthreads();
    for (int kk = 2; kk <= 1024; kk <<= 1) {
        for (int j = kk >> 1; j > 0; j >>= 1) {
            for (int e = t; e < 1024; e += 512) {
                int ixj = e ^ j;
                if (ixj > e) {
                    uint64_t a = key[e], c = key[ixj];
                    bool ddd = ((e & kk) == 0);            // local direction: descending chunk
                    if ((a < c) == ddd) { key[e] = c; key[ixj] = a; }
                }
            }
            __syncthreads();
        }
    }
    for (int i = t; i < 1024; i += 512) cb[base + i] = key[i];
}

// ---------- K4b: merge-path level — merge descending runs of length R into 2R ----------
__launch_bounds__(256)
__global__ void k_merge(int R, const uint64_t* __restrict__ src, uint64_t* __restrict__ dst) {
    int b = blockIdx.y;
    int k = (blockIdx.x << 8) + threadIdx.x;        // [0, 8192)
    const uint64_t* base = src + ((uint64_t)b << 13);
    int run = k / (2 * R);
    int ko = k - run * (2 * R);                     // rank within merged run
    const uint64_t* A = base + (size_t)run * 2 * R;
    const uint64_t* B = A + R;
    int lo = ko - R; if (lo < 0) lo = 0;
    int hi = ko < R ? ko : R;
    while (lo < hi) {
        int m = (lo + hi) >> 1;
        int t = ko - m - 1;
        uint64_t bv = (t < 0) ? ~0ull : (t >= R ? 0ull : B[t]);
        if (A[m] > bv) lo = m + 1; else hi = m;     // A[m] comes before rank ko
    }
    int i = lo, j = ko - lo;
    uint64_t av = (i >= R) ? 0ull : A[i];
    uint64_t bv = (j >= R) ? 0ull : B[j];
    dst[((uint64_t)b << 13) + k] = (av > bv) ? av : bv;
}

// ---------- K4c: final merge level (R=4096) fused with gather+decode ----------
__launch_bounds__(256)
__global__ void k_merge_decode(const uint64_t* __restrict__ src,
                               const float4* __restrict__ rpn_bbox, const float4* __restrict__ anchors,
                               float4* __restrict__ boxes, float* __restrict__ scoresS,
                               float* __restrict__ areas) {
    const int R = 4096;
    int b = blockIdx.y;
    int k = (blockIdx.x << 8) + threadIdx.x;        // [0, 8192)
    if (k >= KPAD2) return;                         // only ranks < 6144 materialized
    const uint64_t* A = src + ((uint64_t)b << 13);
    const uint64_t* B = A + R;
    int lo = k - R; if (lo < 0) lo = 0;
    int hi = k < R ? k : R;
    while (lo < hi) {
        int m = (lo + hi) >> 1;
        int t = k - m - 1;
        uint64_t bv = (t < 0) ? ~0ull : (t >= R ? 0ull : B[t]);
        if (A[m] > bv) lo = m + 1; else hi = m;
    }
    int i = lo, j = k - lo;
    uint64_t av = (i >= R) ? 0ull : A[i];
    uint64_t bv = (j >= R) ? 0ull : B[j];
    uint64_t k64 = (av > bv) ? av : bv;

    float4 bx = make_float4(0.f, 0.f, 0.f, 0.f);
    float sc = 0.f, ar = 0.f;
    if (k < KSEL) {
        uint32_t idx = ~(uint32_t)(k64 & 0xFFFFFFFFull);
        sc = __uint_as_float((uint32_t)(k64 >> 32));
        size_t off = ((size_t)b << 18) + idx;
        float4 a = anchors[off];
        float4 d4 = rpn_bbox[off];
        float d0 = __fmul_rn(d4.x, 0.1f), d1 = __fmul_rn(d4.y, 0.1f);
        float d2 = __fmul_rn(d4.z, 0.2f), d3 = __fmul_rn(d4.w, 0.2f);
        float h = __fsub_rn(a.z, a.x), w = __fsub_rn(a.w, a.y);
        float cy = __fadd_rn(__fadd_rn(a.x, __fmul_rn(0.5f, h)), __fmul_rn(d0, h));
        float cx = __fadd_rn(__fadd_rn(a.y, __fmul_rn(0.5f, w)), __fmul_rn(d1, w));
        float h2 = __fmul_rn(h, expf(d2));
        float w2 = __fmul_rn(w, expf(d3));
        float y1 = __fsub_rn(cy, __fmul_rn(0.5f, h2));
        float x1 = __fsub_rn(cx, __fmul_rn(0.5f, w2));
        float y2 = __fadd_rn(cy, __fmul_rn(0.5f, h2));
        float x2 = __fadd_rn(cx, __fmul_rn(0.5f, w2));
        y1 = fminf(fmaxf(y1, 0.f), 1.f); x1 = fminf(fmaxf(x1, 0.f), 1.f);
        y2 = fminf(fmaxf(y2, 0.f), 1.f); x2 = fminf(fmaxf(x2, 0.f), 1.f);
        bx = make_float4(y1, x1, y2, x2);
        ar = __fmul_rn(__fsub_rn(y2, y1), __fsub_rn(x2, x1));
    }
    boxes[b * KPAD2 + k] = bx;
    scoresS[b * KPAD2 + k] = sc;
    areas[b * KPAD2 + k] = ar;
}

// ---------- K5: suppression bit rows for a word-chunk [w0, ...), 2 rows/thread ----------
__launch_bounds__(128)
__global__ void k_matc(int w0, const float4* __restrict__ boxes, const float* __restrict__ areas,
                       uint64_t* __restrict__ mat, uint64_t* __restrict__ diag,
                       const uint32_t* __restrict__ done) {
    int b = blockIdx.y;
    if (done[b]) return;
    int q = blockIdx.x, W = w0;
    while (q >= W + 1) { q -= W + 1; ++W; }
    int sub = q;                          // [0, W]
    int ibase = sub << 8;
    int t = threadIdx.x;
    __shared__ float4 sb[256];
    __shared__ float sa[256];
    size_t bb = (size_t)b * KPAD2;
    int j0 = W << 8;
    sb[t] = boxes[bb + j0 + t];
    sb[t + 128] = boxes[bb + j0 + t + 128];
    sa[t] = areas[bb + j0 + t];
    sa[t + 128] = areas[bb + j0 + t + 128];
    __syncthreads();
    int iA = ibase + t, iB = ibase + t + 128;
    float4 bA = boxes[bb + iA], bB = boxes[bb + iB];
    float aA = areas[bb + iA], aB = areas[bb + iB];
    uint32_t accA[8] = {0, 0, 0, 0, 0, 0, 0, 0};
    uint32_t accB[8] = {0, 0, 0, 0, 0, 0, 0, 0};
#pragma unroll 4
    for (int jj = 0; jj < 32; ++jj) {
#pragma unroll
        for (int s = 0; s < 4; ++s) {
            int j = (s << 6) + jj;
            float4 bj = sb[j]; float aj = sa[j];
            accA[s * 2] |= sup_bit(bA, aA, bj, aj) << jj;
            accB[s * 2] |= sup_bit(bB, aB, bj, aj) << jj;
        }
    }
#pragma unroll 4
    for (int jj = 32; jj < 64; ++jj) {
#pragma unroll
        for (int s = 0; s < 4; ++s) {
            int j = (s << 6) + jj;
            float4 bj = sb[j]; float aj = sa[j];
            accA[s * 2 + 1] |= sup_bit(bA, aA, bj, aj) << (jj - 32);
            accB[s * 2 + 1] |= sup_bit(bB, aB, bj, aj) << (jj - 32);
        }
    }
    uint64_t* rowA;
    uint64_t* rowB;
    if (sub == W) {
        uint64_t dbase = (uint64_t)b * DIAG_U64_PB;
        rowA = diag + dbase + (uint64_t)(j0 + t) * 4;
        rowB = diag + dbase + (uint64_t)(j0 + t + 128) * 4;
    } else {
        uint64_t mbase = (uint64_t)b * MAT_U64_PB + 512ull * W * (W - 1);
        rowA = mat + mbase + (uint64_t)iA * 4;
        rowB = mat + mbase + (uint64_t)iB * 4;
    }
    ulonglong2 vA0, vA1, vB0, vB1;
    vA0.x = (uint64_t)accA[0] | ((uint64_t)accA[1] << 32);
    vA0.y = (uint64_t)accA[2] | ((uint64_t)accA[3] << 32);
    vA1.x = (uint64_t)accA[4] | ((uint64_t)accA[5] << 32);
    vA1.y = (uint64_t)accA[6] | ((uint64_t)accA[7] << 32);
    vB0.x = (uint64_t)accB[0] | ((uint64_t)accB[1] << 32);
    vB0.y = (uint64_t)accB[2] | ((uint64_t)accB[3] << 32);
    vB1.x = (uint64_t)accB[4] | ((uint64_t)accB[5] << 32);
    vB1.y = (uint64_t)accB[6] | ((uint64_t)accB[7] << 32);
    ((ulonglong2*)rowA)[0] = vA0; ((ulonglong2*)rowA)[1] = vA1;
    ((ulonglong2*)rowB)[0] = vB0; ((ulonglong2*)rowB)[1] = vB1;
}

// ---------- K6: greedy NMS over words [w0,w1); bulk-pick (first-suppressor) ----------
__launch_bounds__(256)
__global__ void k_nms_chunk(int w0, int w1, int final_chunk,
                            const float4* __restrict__ boxes, const float* __restrict__ scoresS,
                            const uint64_t* __restrict__ diag, const uint64_t* __restrict__ mat,
                            uint32_t* __restrict__ gsel, uint32_t* __restrict__ ncount,
                            uint32_t* __restrict__ done, float* __restrict__ out) {
    __shared__ uint32_t sel[PROP];           // 4 KB (global indices)
    __shared__ uint64_t diagrow[256][4];     // 8 KB
    __shared__ uint32_t suppw[8];
    __shared__ uint32_t s_count;

    int b = blockIdx.x;
    if (done[b]) return;
    int tid = threadIdx.x;
    int wid = tid >> 6, lane = tid & 63;
    size_t bb = (size_t)b * KPAD2;
    const uint64_t* mb = mat + (uint64_t)b * MAT_U64_PB;
    const uint64_t* dgb = diag + (uint64_t)b * DIAG_U64_PB;
    uint32_t* gs = gsel + b * 1024;

    int count = (int)ncount[b];
    for (int r = tid; r < count; r += 256) sel[r] = gs[r];
    __syncthreads();

    for (int W = w0; W < w1; ++W) {
        // stage diag rows of word W into LDS; zero suppw
        {
            const ulonglong2* src = (const ulonglong2*)(dgb + (uint64_t)(W << 8) * 4);
            ulonglong2* dst = (ulonglong2*)&diagrow[0][0];
            dst[tid * 2] = src[tid * 2];
            dst[tid * 2 + 1] = src[tid * 2 + 1];
        }
        if (tid < 8) suppw[tid] = 0u;
        __syncthreads();
        // crossing gather: rows of prior selections vs word W (4 slots/thread)
        uint64_t acc0 = 0, acc1 = 0, acc2 = 0, acc3 = 0;
        {
            const uint64_t* col = mb + 512ull * W * (W - 1);
            uint32_t c = (uint32_t)count;
            uint32_t i0 = tid, i1 = tid + 256, i2 = tid + 512, i3 = tid + 768;
            if (i0 < c) { const ulonglong2* r = (const ulonglong2*)(col + 4u * sel[i0]);
                          ulonglong2 x = r[0], y = r[1];
                          acc0 |= x.x; acc1 |= x.y; acc2 |= y.x; acc3 |= y.y; }
            if (i1 < c) { const ulonglong2* r = (const ulonglong2*)(col + 4u * sel[i1]);
                          ulonglong2 x = r[0], y = r[1];
                          acc0 |= x.x; acc1 |= x.y; acc2 |= y.x; acc3 |= y.y; }
            if (i2 < c) { const ulonglong2* r = (const ulonglong2*)(col + 4u * sel[i2]);
                          ulonglong2 x = r[0], y = r[1];
                          acc0 |= x.x; acc1 |= x.y; acc2 |= y.x; acc3 |= y.y; }
            if (i3 < c) { const ulonglong2* r = (const ulonglong2*)(col + 4u * sel[i3]);
                          ulonglong2 x = r[0], y = r[1];
                          acc0 |= x.x; acc1 |= x.y; acc2 |= y.x; acc3 |= y.y; }
        }
#pragma unroll
        for (int off = 32; off; off >>= 1) {
            acc0 |= shfl_xor_u64(acc0, off);
            acc1 |= shfl_xor_u64(acc1, off);
            acc2 |= shfl_xor_u64(acc2, off);
            acc3 |= shfl_xor_u64(acc3, off);
        }
        if (lane == 0) {
            if (acc0) { atomicOr(&suppw[0], (uint32_t)acc0); atomicOr(&suppw[1], (uint32_t)(acc0 >> 32)); }
            if (acc1) { atomicOr(&suppw[2], (uint32_t)acc1); atomicOr(&suppw[3], (uint32_t)(acc1 >> 32)); }
            if (acc2) { atomicOr(&suppw[4], (uint32_t)acc2); atomicOr(&suppw[5], (uint32_t)(acc2 >> 32)); }
            if (acc3) { atomicOr(&suppw[6], (uint32_t)acc3); atomicOr(&suppw[7], (uint32_t)(acc3 >> 32)); }
        }
        __syncthreads();
        int count_old = count;
        // wave 0: bulk greedy selection (first-suppressor batching; proven r12)
        if (wid == 0) {
            uint64_t a0 = ~(((uint64_t)suppw[1] << 32) | suppw[0]);
            uint64_t a1 = ~(((uint64_t)suppw[3] << 32) | suppw[2]);
            uint64_t a2 = ~(((uint64_t)suppw[5] << 32) | suppw[4]);
            uint64_t a3 = ~(((uint64_t)suppw[7] << 32) | suppw[6]);
            if (W == NW2 - 1) { a1 &= (1ull << 48) - 1; a2 = 0; a3 = 0; }   // j < 6000 valid
            uint64_t pk0 = 0, pk1 = 0, pk2 = 0, pk3 = 0;
            uint64_t hi_mask = (lane == 63) ? 0ull : (~0ull << (lane + 1));

#define SUBP(S, AS, PK)                                                       \
            if (AS && count < PROP) {                                         \
                uint64_t own = diagrow[(S << 6) + lane][S];                   \
                while (AS && count < PROP) {                                  \
                    uint32_t alive_l = (uint32_t)((AS >> lane) & 1ull);       \
                    uint64_t inter = own & AS & hi_mask;                      \
                    unsigned long long conf = __ballot(alive_l && (inter != 0ull)); \
                    uint64_t run, rowc = 0ull;                                \
                    if (conf == 0ull) { run = AS; }                           \
                    else {                                                    \
                        uint32_t c = (uint32_t)__builtin_ctzll(conf);         \
                        uint64_t lo = ((1ull << c) << 1) - 1ull;              \
                        run = AS & lo;                                        \
                        rowc = rdlane64(own, c);                              \
                    }                                                         \
                    int pr = (int)__popcll(run);                              \
                    if (count + pr > PROP) {                                  \
                        int need = PROP - count;                              \
                        while (need-- > 0) {                                  \
                            uint32_t bp = (uint32_t)__builtin_ctzll(run);     \
                            PK |= 1ull << bp;                                 \
                            run &= run - 1ull;                                \
                        }                                                     \
                        count = PROP; AS = 0ull;                              \
                    } else {                                                  \
                        PK |= run; count += pr;                               \
                        AS &= ~run; AS &= ~rowc;                              \
                    }                                                         \
                }                                                             \
            }
            SUBP(0, a0, pk0)
            // transition: picked subword-0 boxes suppress subwords 1..3
            if (pk0 && count < PROP) {
                uint32_t pl = (uint32_t)((pk0 >> lane) & 1ull);
                uint64_t x1 = pl ? diagrow[lane][1] : 0ull;
                uint64_t x2 = pl ? diagrow[lane][2] : 0ull;
                uint64_t x3 = pl ? diagrow[lane][3] : 0ull;
#pragma unroll
                for (int off = 32; off; off >>= 1) {
                    x1 |= shfl_xor_u64(x1, off);
                    x2 |= shfl_xor_u64(x2, off);
                    x3 |= shfl_xor_u64(x3, off);
                }
                a1 &= ~rdfl64(x1); a2 &= ~rdfl64(x2); a3 &= ~rdfl64(x3);
            }
            SUBP(1, a1, pk1)
            if (pk1 && count < PROP) {
                uint32_t pl = (uint32_t)((pk1 >> lane) & 1ull);
                uint64_t x2 = pl ? diagrow[64 + lane][2] : 0ull;
                uint64_t x3 = pl ? diagrow[64 + lane][3] : 0ull;
#pragma unroll
                for (int off = 32; off; off >>= 1) {
                    x2 |= shfl_xor_u64(x2, off);
                    x3 |= shfl_xor_u64(x3, off);
                }
                a2 &= ~rdfl64(x2); a3 &= ~rdfl64(x3);
            }
            SUBP(2, a2, pk2)
            if (pk2 && count < PROP) {
                uint32_t pl = (uint32_t)((pk2 >> lane) & 1ull);
                uint64_t x3 = pl ? diagrow[128 + lane][3] : 0ull;
#pragma unroll
                for (int off = 32; off; off >>= 1) x3 |= shfl_xor_u64(x3, off);
                a3 &= ~rdfl64(x3);
            }
            SUBP(3, a3, pk3)
#undef SUBP
            // parallel append: picks were made in ascending (S, bp) order
            uint32_t nb = (uint32_t)count_old;
#define APPEND(S, PK) {                                                       \
            if (PK) {                                                         \
                uint32_t my = (uint32_t)((PK >> lane) & 1ull);                \
                uint32_t rank = (uint32_t)__popcll(PK & ((1ull << lane) - 1ull));\
                if (my) {                                                     \
                    uint32_t v = (uint32_t)((W << 8) + (S << 6) + lane);      \
                    sel[nb + rank] = v;                                       \
                    gs[nb + rank] = v;                                        \
                }                                                             \
                nb += (uint32_t)__popcll(PK);                                 \
            } }
            APPEND(0, pk0)
            APPEND(1, pk1)
            APPEND(2, pk2)
            APPEND(3, pk3)
#undef APPEND
            if (lane == 0) s_count = (uint32_t)count;
        }
        __syncthreads();
        count = (int)s_count;
        if (count >= PROP) break;
    }

    if (count >= PROP || final_chunk) {
        if (tid == 0) { done[b] = 1u; ncount[b] = (uint32_t)count; }
        float* prop = out + b * (PROP * 4);
        float* psc = out + BB * PROP * 4 + b * PROP;
        for (int r = tid; r < PROP; r += 256) {
            if (r < count) {
                uint32_t j = sel[r];
                float4 bx = boxes[bb + j];
                *(float4*)(prop + r * 4) = bx;
                psc[r] = scoresS[bb + j];
            } else {
                *(float4*)(prop + r * 4) = make_float4(0.f, 0.f, 0.f, 0.f);
                psc[r] = 0.f;
            }
        }
    } else {
        if (tid == 0) ncount[b] = (uint32_t)count;
    }
}

extern "C" void kernel_launch(void* const* d_in, const int* in_sizes, int n_in,
                              void* d_out, int out_size, void* d_ws, size_t ws_size,
                              hipStream_t stream) {
    const float4* probs = (const float4*)d_in[0];
    const float4* rpn_bbox = (const float4*)d_in[1];
    const float4* anchors = (const float4*)d_in[2];
    float* out = (float*)d_out;

    uint8_t* p = (uint8_t*)d_ws;
    size_t off = 0;
    auto alloc = [&](size_t bytes) -> void* {
        void* q = p + off;
        off += (bytes + 255) & ~(size_t)255;
        return q;
    };
    uint32_t* ghist = (uint32_t*)alloc((size_t)BB * 256 * 4);              // 8 KB
    uint32_t* cnt = (uint32_t*)alloc(BB * 4);
    uint32_t* ncount = (uint32_t*)alloc(BB * 4);
    uint32_t* ndone = (uint32_t*)alloc(BB * 4);
    uint64_t* cand = (uint64_t*)alloc((size_t)BB * CAND_CAP * 8);          // 512 KB
    uint64_t* cand2 = (uint64_t*)alloc((size_t)BB * CAND_CAP * 8);         // 512 KB
    float4* boxes = (float4*)alloc((size_t)BB * KPAD2 * 16);               // 768 KB
    float* scoresS = (float*)alloc((size_t)BB * KPAD2 * 4);
    float* areas = (float*)alloc((size_t)BB * KPAD2 * 4);
    uint32_t* gsel = (uint32_t*)alloc((size_t)BB * 1024 * 4);              // 32 KB
    uint64_t* diag = (uint64_t*)alloc((size_t)BB * DIAG_U64_PB * 8);       // 1.57 MB
    uint64_t* mat = (uint64_t*)alloc((size_t)BB * MAT_U64_PB * 8);         // 18.1 MB

    if (off > ws_size) {
        hipMemsetAsync(d_out, 0, (size_t)out_size * 4, stream);
        return;
    }

    // zero ghist + cnt + ncount + ndone with our own kernel (rocclr fillBuffer
    // for this 8.75 KB region measured ~40 us on-device — pathological path)
    k_zero<<<BB, 256, 0, stream>>>(ghist, cnt, ncount, ndone);

    k_hist<<<BB * BPB, 256, 0, stream>>>(probs, ghist);
    k_compact<<<BB * BPB, 256, 0, stream>>>(probs, ghist, cnt, cand);
    dim3 gs1(8, BB);
    k_sort1<<<gs1, 512, 0, stream>>>(cnt, cand);
    dim3 gmg(32, BB);
    k_merge<<<gmg, 256, 0, stream>>>(1024, cand, cand2);
    k_merge<<<gmg, 256, 0, stream>>>(2048, cand2, cand);
    dim3 gmd(24, BB);   // 24*256 = 6144 ranks materialized
    k_merge_decode<<<gmd, 256, 0, stream>>>(cand, rpn_bbox, anchors, boxes, scoresS, areas);

    const int cb[3] = {0, 6, 24};
    for (int c = 0; c < 2; ++c) {
        int w0 = cb[c], w1 = cb[c + 1];
        int nblk = 0;
        for (int W = w0; W < w1; ++W) nblk += W + 1;
        dim3 gm(nblk, BB);
        k_matc<<<gm, 128, 0, stream>>>(w0, boxes, areas, mat, diag, ndone);
        k_nms_chunk<<<BB, 256, 0, stream>>>(w0, w1, (w1 == NW2) ? 1 : 0,
                                            boxes, scoresS, diag, mat,
                                            gsel, ncount, ndone, out);
    }
}

// Round 15
// 101.602 us; speedup vs baseline: 3.4069x; 1.0948x over previous
//
#include <hip/hip_runtime.h>
#include <stdint.h>

#define BB 8
#define NN 262144
#define KSEL 6000
#define KPAD2 6144
#define NW2 24               // 24 words of 256 boxes
#define PROP 1000
#define NMS_THR 0.7f
#define CAND_CAP 8192
#define BPB 64               // blocks per batch for hist/compact (4096 items each)
#define STAGE_CAP 768
#define MAT_U64_PB 282624ull // sum_{W=1..23} 256*W rows * 4 u64 = 512*23*24
#define DIAG_U64_PB 24576ull // 24*256*4

// ---------- helpers ----------
__device__ __forceinline__ unsigned long long shfl_xor_u64(unsigned long long v, int m) {
    unsigned lo = (unsigned)v, hi = (unsigned)(v >> 32);
    lo = __shfl_xor(lo, m);
    hi = __shfl_xor(hi, m);
    return ((unsigned long long)hi << 32) | lo;
}
__device__ __forceinline__ uint64_t rdfl64(uint64_t v) {
    uint32_t lo = __builtin_amdgcn_readfirstlane((uint32_t)v);
    uint32_t hi = __builtin_amdgcn_readfirstlane((uint32_t)(v >> 32));
    return ((uint64_t)hi << 32) | lo;
}
__device__ __forceinline__ uint64_t rdlane64(uint64_t v, uint32_t l) {
    uint32_t lo = __builtin_amdgcn_readlane((uint32_t)v, l);
    uint32_t hi = __builtin_amdgcn_readlane((uint32_t)(v >> 32), l);
    return ((uint64_t)hi << 32) | lo;
}

// Exact replacement for RN(inter/den) > 0.7f (den > 0 always):
//   RN(q) > c  <=>  q >= M, M = c + 2^-25 (midpoint; tie rounds to even = c_next > c).
//   M has 25-bit significand, den 24 bits -> M*den exact in f64; comparison exact.
__device__ __forceinline__ uint32_t sup_bit(const float4 bi, float ai, const float4 bj, float aj) {
    float y1 = fmaxf(bi.x, bj.x), x1 = fmaxf(bi.y, bj.y);
    float y2 = fminf(bi.z, bj.z), x2 = fminf(bi.w, bj.w);
    float inter = __fmul_rn(fmaxf(__fsub_rn(y2, y1), 0.f), fmaxf(__fsub_rn(x2, x1), 0.f));
    float den = __fadd_rn(__fsub_rn(__fadd_rn(ai, aj), inter), 1e-10f);
    const double MSUP = 23488103.0 / 33554432.0;   // 0.7f + 2^-25, exact
    return (double)inter >= MSUP * (double)den;
}

__device__ __forceinline__ uint32_t score_bin(float sc) {
    uint32_t u = (uint32_t)(sc * 16777216.0f);
    u = u > 16777215u ? 16777215u : u;
    return u >> 16;
}

// ---------- K0: zero the small state ----------
__global__ void k_zero(uint32_t* __restrict__ ghist, uint32_t* __restrict__ cnt,
                       uint32_t* __restrict__ ncount, uint32_t* __restrict__ ndone) {
    int b = blockIdx.x, t = threadIdx.x;
    ghist[(b << 8) + t] = 0u;
    if (t == 0) { cnt[b] = 0u; ncount[b] = 0u; ndone[b] = 0u; }
}

// ---------- K1: per-block LDS histogram -> global 256-bin per-batch hist ----------
__global__ void k_hist(const float4* __restrict__ probs, uint32_t* __restrict__ ghist) {
    __shared__ uint32_t lh[256];
    int blk = blockIdx.x;
    int b = blk >> 6;
    int t = threadIdx.x;
    lh[t] = 0u;
    __syncthreads();
    size_t fbase = ((size_t)b * (NN / 2)) + (size_t)(blk & 63) * 2048;
#pragma unroll
    for (int k = 0; k < 8; ++k) {
        float4 v = probs[fbase + k * 256 + t];
        atomicAdd(&lh[score_bin(v.y)], 1u);
        atomicAdd(&lh[score_bin(v.w)], 1u);
    }
    __syncthreads();
    uint32_t c = lh[t];
    if (c) atomicAdd(&ghist[(b << 8) + t], c);
}

// ---------- K3: compact candidates (threshold derived in-block), block-aggregated ----------
__global__ void k_compact(const float4* __restrict__ probs, const uint32_t* __restrict__ ghist,
                          uint32_t* __restrict__ cnt, uint64_t* __restrict__ cand) {
    __shared__ uint64_t stage[STAGE_CAP];
    __shared__ uint32_t lh[256];
    __shared__ uint32_t s_bst, lcnt, lbase;
    int blk = blockIdx.x;
    int b = blk >> 6;
    int t = threadIdx.x;
    lh[t] = ghist[(b << 8) + t];
    if (t == 0) lcnt = 0u;
    __syncthreads();
    if (t == 0) {
        uint32_t cum = 0; uint32_t bst = 0;
        for (int c = 255; c >= 0; --c) {
            cum += lh[c];
            if (cum >= (uint32_t)KSEL) { bst = (uint32_t)c; break; }
        }
        s_bst = bst;
    }
    __syncthreads();
    uint32_t bst = s_bst;
    int ibase = (blk & 63) * 4096;
    size_t fbase = ((size_t)b * (NN / 2)) + (size_t)(blk & 63) * 2048;
#pragma unroll
    for (int k = 0; k < 8; ++k) {
        float4 v = probs[fbase + k * 256 + t];
        int i0 = ibase + (k * 256 + t) * 2;
#pragma unroll
        for (int e = 0; e < 2; ++e) {
            float sc = e ? v.w : v.y;
            if (score_bin(sc) >= bst) {
                uint32_t p = atomicAdd(&lcnt, 1u);
                if (p < STAGE_CAP) {
                    uint32_t bits = __float_as_uint(sc);
                    stage[p] = ((uint64_t)bits << 32) | (uint32_t)(~(uint32_t)(i0 + e));
                }
            }
        }
    }
    __syncthreads();
    if (t == 0) {
        uint32_t m = lcnt > STAGE_CAP ? STAGE_CAP : lcnt;
        lbase = atomicAdd(&cnt[b], m);
        lcnt = m;
    }
    __syncthreads();
    uint32_t m = lcnt, base = lbase;
    for (uint32_t s = t; s < m; s += 256) {
        uint32_t pos = base + s;
        if (pos < CAND_CAP) cand[((uint64_t)b << 13) + pos] = stage[s];
    }
}

// ---------- K4a: bitonic phase A — sort each 1024-chunk DESCENDING (local dir) ----------
__launch_bounds__(512)
__global__ void k_sort1(const uint32_t* __restrict__ cnt, uint64_t* __restrict__ cand) {
    __shared__ uint64_t key[1024];
    int b = blockIdx.y, ch = blockIdx.x, t = threadIdx.x;
    uint32_t M = cnt[b]; if (M > CAND_CAP) M = CAND_CAP;
    uint64_t* cb = cand + ((uint64_t)b << 13);
    int base = ch << 10;
    for (int i = t; i < 1024; i += 512) key[i] = ((uint32_t)(base + i) < M) ? cb[base + i] : 0ull;
    __syncthreads();
    for (int kk = 2; kk <= 1024; kk <<= 1) {
        for (int j = kk >> 1; j > 0; j >>= 1) {
            for (int e = t; e < 1024; e += 512) {
                int ixj = e ^ j;
                if (ixj > e) {
                    uint64_t a = key[e], c = key[ixj];
                    bool ddd = ((e & kk) == 0);            // local direction: descending chunk
                    if ((a < c) == ddd) { key[e] = c; key[ixj] = a; }
                }
            }
            __syncthreads();
        }
    }
    for (int i = t; i < 1024; i += 512) cb[base + i] = key[i];
}

// ---------- K4b: merge-path level — merge descending runs of length R into 2R ----------
__launch_bounds__(256)
__global__ void k_merge(int R, const uint64_t* __restrict__ src, uint64_t* __restrict__ dst) {
    int b = blockIdx.y;
    int k = (blockIdx.x << 8) + threadIdx.x;        // [0, 8192)
    const uint64_t* base = src + ((uint64_t)b << 13);
    int run = k / (2 * R);
    int ko = k - run * (2 * R);                     // rank within merged run
    const uint64_t* A = base + (size_t)run * 2 * R;
    const uint64_t* B = A + R;
    int lo = ko - R; if (lo < 0) lo = 0;
    int hi = ko < R ? ko : R;
    while (lo < hi) {
        int m = (lo + hi) >> 1;
        int t = ko - m - 1;
        uint64_t bv = (t < 0) ? ~0ull : (t >= R ? 0ull : B[t]);
        if (A[m] > bv) lo = m + 1; else hi = m;     // A[m] comes before rank ko
    }
    int i = lo, j = ko - lo;
    uint64_t av = (i >= R) ? 0ull : A[i];
    uint64_t bv = (j >= R) ? 0ull : B[j];
    dst[((uint64_t)b << 13) + k] = (av > bv) ? av : bv;
}

// ---------- K4c: final merge level (R=4096) fused with gather+decode ----------
__launch_bounds__(256)
__global__ void k_merge_decode(const uint64_t* __restrict__ src,
                               const float4* __restrict__ rpn_bbox, const float4* __restrict__ anchors,
                               float4* __restrict__ boxes, float* __restrict__ scoresS,
                               float* __restrict__ areas) {
    const int R = 4096;
    int b = blockIdx.y;
    int k = (blockIdx.x << 8) + threadIdx.x;        // [0, 8192)
    if (k >= KPAD2) return;                         // only ranks < 6144 materialized
    const uint64_t* A = src + ((uint64_t)b << 13);
    const uint64_t* B = A + R;
    int lo = k - R; if (lo < 0) lo = 0;
    int hi = k < R ? k : R;
    while (lo < hi) {
        int m = (lo + hi) >> 1;
        int t = k - m - 1;
        uint64_t bv = (t < 0) ? ~0ull : (t >= R ? 0ull : B[t]);
        if (A[m] > bv) lo = m + 1; else hi = m;
    }
    int i = lo, j = k - lo;
    uint64_t av = (i >= R) ? 0ull : A[i];
    uint64_t bv = (j >= R) ? 0ull : B[j];
    uint64_t k64 = (av > bv) ? av : bv;

    float4 bx = make_float4(0.f, 0.f, 0.f, 0.f);
    float sc = 0.f, ar = 0.f;
    if (k < KSEL) {
        uint32_t idx = ~(uint32_t)(k64 & 0xFFFFFFFFull);
        sc = __uint_as_float((uint32_t)(k64 >> 32));
        size_t off = ((size_t)b << 18) + idx;
        float4 a = anchors[off];
        float4 d4 = rpn_bbox[off];
        float d0 = __fmul_rn(d4.x, 0.1f), d1 = __fmul_rn(d4.y, 0.1f);
        float d2 = __fmul_rn(d4.z, 0.2f), d3 = __fmul_rn(d4.w, 0.2f);
        float h = __fsub_rn(a.z, a.x), w = __fsub_rn(a.w, a.y);
        float cy = __fadd_rn(__fadd_rn(a.x, __fmul_rn(0.5f, h)), __fmul_rn(d0, h));
        float cx = __fadd_rn(__fadd_rn(a.y, __fmul_rn(0.5f, w)), __fmul_rn(d1, w));
        float h2 = __fmul_rn(h, expf(d2));
        float w2 = __fmul_rn(w, expf(d3));
        float y1 = __fsub_rn(cy, __fmul_rn(0.5f, h2));
        float x1 = __fsub_rn(cx, __fmul_rn(0.5f, w2));
        float y2 = __fadd_rn(cy, __fmul_rn(0.5f, h2));
        float x2 = __fadd_rn(cx, __fmul_rn(0.5f, w2));
        y1 = fminf(fmaxf(y1, 0.f), 1.f); x1 = fminf(fmaxf(x1, 0.f), 1.f);
        y2 = fminf(fmaxf(y2, 0.f), 1.f); x2 = fminf(fmaxf(x2, 0.f), 1.f);
        bx = make_float4(y1, x1, y2, x2);
        ar = __fmul_rn(__fsub_rn(y2, y1), __fsub_rn(x2, x1));
    }
    boxes[b * KPAD2 + k] = bx;
    scoresS[b * KPAD2 + k] = sc;
    areas[b * KPAD2 + k] = ar;
}

// ---------- K5: suppression bit rows, 1 row/thread, column-half split ----------
// blockIdx.x encodes (W, sub, half): half = low bit; (W,sub) decoded from q>>1.
// Each block: 256 rows (one per thread) x 128 columns (subwords 2h, 2h+1).
// 4x the waves and 1/4 the per-thread chain vs the 2-row/128-thread version
// (which ran at 0.33 waves/SIMD and was latency-bound at 39 us).
__launch_bounds__(256)
__global__ void k_matc(int w0, const float4* __restrict__ boxes, const float* __restrict__ areas,
                       uint64_t* __restrict__ mat, uint64_t* __restrict__ diag,
                       const uint32_t* __restrict__ done) {
    int b = blockIdx.y;
    if (done[b]) return;
    int q2 = blockIdx.x;
    int half = q2 & 1;
    int q = q2 >> 1, W = w0;
    while (q >= W + 1) { q -= W + 1; ++W; }
    int sub = q;                          // [0, W]
    int t = threadIdx.x;
    __shared__ float4 sb[128];
    __shared__ float sa[128];
    size_t bb = (size_t)b * KPAD2;
    int j0 = (W << 8) + (half << 7);      // 128 columns of word W
    if (t < 128) { sb[t] = boxes[bb + j0 + t]; sa[t] = areas[bb + j0 + t]; }
    __syncthreads();
    int i = (sub << 8) + t;               // this thread's row
    float4 bi = boxes[bb + i];
    float ai = areas[bb + i];
    uint32_t a0 = 0, a1 = 0, a2 = 0, a3 = 0;
#pragma unroll 4
    for (int jj = 0; jj < 32; ++jj) {
        a0 |= sup_bit(bi, ai, sb[jj], sa[jj]) << jj;
        a1 |= sup_bit(bi, ai, sb[32 + jj], sa[32 + jj]) << jj;
        a2 |= sup_bit(bi, ai, sb[64 + jj], sa[64 + jj]) << jj;
        a3 |= sup_bit(bi, ai, sb[96 + jj], sa[96 + jj]) << jj;
    }
    uint64_t* row;
    if (sub == W) {
        row = diag + (uint64_t)b * DIAG_U64_PB + (uint64_t)(j0 & ~127) * 0 // keep expression simple
              + (uint64_t)((W << 8) + t) * 4;
    } else {
        row = mat + (uint64_t)b * MAT_U64_PB + 512ull * W * (W - 1) + (uint64_t)i * 4;
    }
    ulonglong2 v;
    v.x = (uint64_t)a0 | ((uint64_t)a1 << 32);    // subword 2h
    v.y = (uint64_t)a2 | ((uint64_t)a3 << 32);    // subword 2h+1
    *(ulonglong2*)(row + (half << 1)) = v;
}

// ---------- K6: greedy NMS over words [w0,w1); bulk-pick (first-suppressor) ----------
__launch_bounds__(256)
__global__ void k_nms_chunk(int w0, int w1, int final_chunk,
                            const float4* __restrict__ boxes, const float* __restrict__ scoresS,
                            const uint64_t* __restrict__ diag, const uint64_t* __restrict__ mat,
                            uint32_t* __restrict__ gsel, uint32_t* __restrict__ ncount,
                            uint32_t* __restrict__ done, float* __restrict__ out) {
    __shared__ uint32_t sel[PROP];           // 4 KB (global indices)
    __shared__ uint64_t diagrow[256][4];     // 8 KB
    __shared__ uint32_t suppw[8];
    __shared__ uint32_t s_count;

    int b = blockIdx.x;
    if (done[b]) return;
    int tid = threadIdx.x;
    int wid = tid >> 6, lane = tid & 63;
    size_t bb = (size_t)b * KPAD2;
    const uint64_t* mb = mat + (uint64_t)b * MAT_U64_PB;
    const uint64_t* dgb = diag + (uint64_t)b * DIAG_U64_PB;
    uint32_t* gs = gsel + b * 1024;

    int count = (int)ncount[b];
    for (int r = tid; r < count; r += 256) sel[r] = gs[r];
    __syncthreads();

    for (int W = w0; W < w1; ++W) {
        // stage diag rows of word W into LDS; zero suppw
        {
            const ulonglong2* src = (const ulonglong2*)(dgb + (uint64_t)(W << 8) * 4);
            ulonglong2* dst = (ulonglong2*)&diagrow[0][0];
            dst[tid * 2] = src[tid * 2];
            dst[tid * 2 + 1] = src[tid * 2 + 1];
        }
        if (tid < 8) suppw[tid] = 0u;
        __syncthreads();
        // crossing gather: rows of prior selections vs word W (4 slots/thread)
        uint64_t acc0 = 0, acc1 = 0, acc2 = 0, acc3 = 0;
        {
            const uint64_t* col = mb + 512ull * W * (W - 1);
            uint32_t c = (uint32_t)count;
            uint32_t i0 = tid, i1 = tid + 256, i2 = tid + 512, i3 = tid + 768;
            if (i0 < c) { const ulonglong2* r = (const ulonglong2*)(col + 4u * sel[i0]);
                          ulonglong2 x = r[0], y = r[1];
                          acc0 |= x.x; acc1 |= x.y; acc2 |= y.x; acc3 |= y.y; }
            if (i1 < c) { const ulonglong2* r = (const ulonglong2*)(col + 4u * sel[i1]);
                          ulonglong2 x = r[0], y = r[1];
                          acc0 |= x.x; acc1 |= x.y; acc2 |= y.x; acc3 |= y.y; }
            if (i2 < c) { const ulonglong2* r = (const ulonglong2*)(col + 4u * sel[i2]);
                          ulonglong2 x = r[0], y = r[1];
                          acc0 |= x.x; acc1 |= x.y; acc2 |= y.x; acc3 |= y.y; }
            if (i3 < c) { const ulonglong2* r = (const ulonglong2*)(col + 4u * sel[i3]);
                          ulonglong2 x = r[0], y = r[1];
                          acc0 |= x.x; acc1 |= x.y; acc2 |= y.x; acc3 |= y.y; }
        }
#pragma unroll
        for (int off = 32; off; off >>= 1) {
            acc0 |= shfl_xor_u64(acc0, off);
            acc1 |= shfl_xor_u64(acc1, off);
            acc2 |= shfl_xor_u64(acc2, off);
            acc3 |= shfl_xor_u64(acc3, off);
        }
        if (lane == 0) {
            if (acc0) { atomicOr(&suppw[0], (uint32_t)acc0); atomicOr(&suppw[1], (uint32_t)(acc0 >> 32)); }
            if (acc1) { atomicOr(&suppw[2], (uint32_t)acc1); atomicOr(&suppw[3], (uint32_t)(acc1 >> 32)); }
            if (acc2) { atomicOr(&suppw[4], (uint32_t)acc2); atomicOr(&suppw[5], (uint32_t)(acc2 >> 32)); }
            if (acc3) { atomicOr(&suppw[6], (uint32_t)acc3); atomicOr(&suppw[7], (uint32_t)(acc3 >> 32)); }
        }
        __syncthreads();
        int count_old = count;
        // wave 0: bulk greedy selection (first-suppressor batching; proven r12)
        if (wid == 0) {
            uint64_t a0 = ~(((uint64_t)suppw[1] << 32) | suppw[0]);
            uint64_t a1 = ~(((uint64_t)suppw[3] << 32) | suppw[2]);
            uint64_t a2 = ~(((uint64_t)suppw[5] << 32) | suppw[4]);
            uint64_t a3 = ~(((uint64_t)suppw[7] << 32) | suppw[6]);
            if (W == NW2 - 1) { a1 &= (1ull << 48) - 1; a2 = 0; a3 = 0; }   // j < 6000 valid
            uint64_t pk0 = 0, pk1 = 0, pk2 = 0, pk3 = 0;
            uint64_t hi_mask = (lane == 63) ? 0ull : (~0ull << (lane + 1));

#define SUBP(S, AS, PK)                                                       \
            if (AS && count < PROP) {                                         \
                uint64_t own = diagrow[(S << 6) + lane][S];                   \
                while (AS && count < PROP) {                                  \
                    uint32_t alive_l = (uint32_t)((AS >> lane) & 1ull);       \
                    uint64_t inter = own & AS & hi_mask;                      \
                    unsigned long long conf = __ballot(alive_l && (inter != 0ull)); \
                    uint64_t run, rowc = 0ull;                                \
                    if (conf == 0ull) { run = AS; }                           \
                    else {                                                    \
                        uint32_t c = (uint32_t)__builtin_ctzll(conf);         \
                        uint64_t lo = ((1ull << c) << 1) - 1ull;              \
                        run = AS & lo;                                        \
                        rowc = rdlane64(own, c);                              \
                    }                                                         \
                    int pr = (int)__popcll(run);                              \
                    if (count + pr > PROP) {                                  \
                        int need = PROP - count;                              \
                        while (need-- > 0) {                                  \
                            uint32_t bp = (uint32_t)__builtin_ctzll(run);     \
                            PK |= 1ull << bp;                                 \
                            run &= run - 1ull;                                \
                        }                                                     \
                        count = PROP; AS = 0ull;                              \
                    } else {                                                  \
                        PK |= run; count += pr;                               \
                        AS &= ~run; AS &= ~rowc;                              \
                    }                                                         \
                }                                                             \
            }
            SUBP(0, a0, pk0)
            // transition: picked subword-0 boxes suppress subwords 1..3
            if (pk0 && count < PROP) {
                uint32_t pl = (uint32_t)((pk0 >> lane) & 1ull);
                uint64_t x1 = pl ? diagrow[lane][1] : 0ull;
                uint64_t x2 = pl ? diagrow[lane][2] : 0ull;
                uint64_t x3 = pl ? diagrow[lane][3] : 0ull;
#pragma unroll
                for (int off = 32; off; off >>= 1) {
                    x1 |= shfl_xor_u64(x1, off);
                    x2 |= shfl_xor_u64(x2, off);
                    x3 |= shfl_xor_u64(x3, off);
                }
                a1 &= ~rdfl64(x1); a2 &= ~rdfl64(x2); a3 &= ~rdfl64(x3);
            }
            SUBP(1, a1, pk1)
            if (pk1 && count < PROP) {
                uint32_t pl = (uint32_t)((pk1 >> lane) & 1ull);
                uint64_t x2 = pl ? diagrow[64 + lane][2] : 0ull;
                uint64_t x3 = pl ? diagrow[64 + lane][3] : 0ull;
#pragma unroll
                for (int off = 32; off; off >>= 1) {
                    x2 |= shfl_xor_u64(x2, off);
                    x3 |= shfl_xor_u64(x3, off);
                }
                a2 &= ~rdfl64(x2); a3 &= ~rdfl64(x3);
            }
            SUBP(2, a2, pk2)
            if (pk2 && count < PROP) {
                uint32_t pl = (uint32_t)((pk2 >> lane) & 1ull);
                uint64_t x3 = pl ? diagrow[128 + lane][3] : 0ull;
#pragma unroll
                for (int off = 32; off; off >>= 1) x3 |= shfl_xor_u64(x3, off);
                a3 &= ~rdfl64(x3);
            }
            SUBP(3, a3, pk3)
#undef SUBP
            // parallel append: picks were made in ascending (S, bp) order
            uint32_t nb = (uint32_t)count_old;
#define APPEND(S, PK) {                                                       \
            if (PK) {                                                         \
                uint32_t my = (uint32_t)((PK >> lane) & 1ull);                \
                uint32_t rank = (uint32_t)__popcll(PK & ((1ull << lane) - 1ull));\
                if (my) {                                                     \
                    uint32_t v = (uint32_t)((W << 8) + (S << 6) + lane);      \
                    sel[nb + rank] = v;                                       \
                    gs[nb + rank] = v;                                        \
                }                                                             \
                nb += (uint32_t)__popcll(PK);                                 \
            } }
            APPEND(0, pk0)
            APPEND(1, pk1)
            APPEND(2, pk2)
            APPEND(3, pk3)
#undef APPEND
            if (lane == 0) s_count = (uint32_t)count;
        }
        __syncthreads();
        count = (int)s_count;
        if (count >= PROP) break;
    }

    if (count >= PROP || final_chunk) {
        if (tid == 0) { done[b] = 1u; ncount[b] = (uint32_t)count; }
        float* prop = out + b * (PROP * 4);
        float* psc = out + BB * PROP * 4 + b * PROP;
        for (int r = tid; r < PROP; r += 256) {
            if (r < count) {
                uint32_t j = sel[r];
                float4 bx = boxes[bb + j];
                *(float4*)(prop + r * 4) = bx;
                psc[r] = scoresS[bb + j];
            } else {
                *(float4*)(prop + r * 4) = make_float4(0.f, 0.f, 0.f, 0.f);
                psc[r] = 0.f;
            }
        }
    } else {
        if (tid == 0) ncount[b] = (uint32_t)count;
    }
}

extern "C" void kernel_launch(void* const* d_in, const int* in_sizes, int n_in,
                              void* d_out, int out_size, void* d_ws, size_t ws_size,
                              hipStream_t stream) {
    const float4* probs = (const float4*)d_in[0];
    const float4* rpn_bbox = (const float4*)d_in[1];
    const float4* anchors = (const float4*)d_in[2];
    float* out = (float*)d_out;

    uint8_t* p = (uint8_t*)d_ws;
    size_t off = 0;
    auto alloc = [&](size_t bytes) -> void* {
        void* q = p + off;
        off += (bytes + 255) & ~(size_t)255;
        return q;
    };
    uint32_t* ghist = (uint32_t*)alloc((size_t)BB * 256 * 4);              // 8 KB
    uint32_t* cnt = (uint32_t*)alloc(BB * 4);
    uint32_t* ncount = (uint32_t*)alloc(BB * 4);
    uint32_t* ndone = (uint32_t*)alloc(BB * 4);
    uint64_t* cand = (uint64_t*)alloc((size_t)BB * CAND_CAP * 8);          // 512 KB
    uint64_t* cand2 = (uint64_t*)alloc((size_t)BB * CAND_CAP * 8);         // 512 KB
    float4* boxes = (float4*)alloc((size_t)BB * KPAD2 * 16);               // 768 KB
    float* scoresS = (float*)alloc((size_t)BB * KPAD2 * 4);
    float* areas = (float*)alloc((size_t)BB * KPAD2 * 4);
    uint32_t* gsel = (uint32_t*)alloc((size_t)BB * 1024 * 4);              // 32 KB
    uint64_t* diag = (uint64_t*)alloc((size_t)BB * DIAG_U64_PB * 8);       // 1.57 MB
    uint64_t* mat = (uint64_t*)alloc((size_t)BB * MAT_U64_PB * 8);         // 18.1 MB

    if (off > ws_size) {
        hipMemsetAsync(d_out, 0, (size_t)out_size * 4, stream);
        return;
    }

    k_zero<<<BB, 256, 0, stream>>>(ghist, cnt, ncount, ndone);

    k_hist<<<BB * BPB, 256, 0, stream>>>(probs, ghist);
    k_compact<<<BB * BPB, 256, 0, stream>>>(probs, ghist, cnt, cand);
    dim3 gs1(8, BB);
    k_sort1<<<gs1, 512, 0, stream>>>(cnt, cand);
    dim3 gmg(32, BB);
    k_merge<<<gmg, 256, 0, stream>>>(1024, cand, cand2);
    k_merge<<<gmg, 256, 0, stream>>>(2048, cand2, cand);
    dim3 gmd(24, BB);   // 24*256 = 6144 ranks materialized
    k_merge_decode<<<gmd, 256, 0, stream>>>(cand, rpn_bbox, anchors, boxes, scoresS, areas);

    const int cb[3] = {0, 6, 24};
    for (int c = 0; c < 2; ++c) {
        int w0 = cb[c], w1 = cb[c + 1];
        int nblk = 0;
        for (int W = w0; W < w1; ++W) nblk += W + 1;
        dim3 gm(nblk * 2, BB);   // x2: column-half split
        k_matc<<<gm, 256, 0, stream>>>(w0, boxes, areas, mat, diag, ndone);
        k_nms_chunk<<<BB, 256, 0, stream>>>(w0, w1, (w1 == NW2) ? 1 : 0,
                                            boxes, scoresS, diag, mat,
                                            gsel, ncount, ndone, out);
    }
}